// Round 1
// baseline (2319.111 us; speedup 1.0000x reference)
//
#include <hip/hip_runtime.h>
#include <hip/hip_bf16.h>

#define TLEN 4096
#define RCH 512
#define GCH 512
#define SCH 512
#define CINCH 128
#define HPAD 512
#define HSTRIDE (TLEN + HPAD)
#define SQRT_HALF 0.70710678118654752f

typedef __attribute__((ext_vector_type(8))) short short8;
typedef __attribute__((ext_vector_type(4))) float floatx4;

#define MFMA_BF16(a, b, c) __builtin_amdgcn_mfma_f32_16x16x32_bf16((a), (b), (c), 0, 0, 0)

__device__ __forceinline__ float bf2f(unsigned short u) {
  union { unsigned int i; float f; } v; v.i = ((unsigned int)u) << 16; return v.f;
}
__device__ __forceinline__ unsigned short f2bf(float x) {
  union { float f; unsigned int i; } v; v.f = x;
  unsigned int r = v.i + 0x7FFFu + ((v.i >> 16) & 1u);
  return (unsigned short)(r >> 16);
}

// ---------------- upsample stage 1: c[128][16] -> u1[128][256] ----------------
__global__ __launch_bounds__(256) void upsample1_kernel(
    const float* __restrict__ c, const float* __restrict__ up_w,
    const float* __restrict__ up_b, float* __restrict__ u1)
{
  int x = threadIdx.x;        // 0..255
  int h = blockIdx.x;         // 0..127
  const float* w = up_w;      // stage 0 kernel [3][32]
  float acc = 0.f;
  int k1 = (23 - x) & 15;
  #pragma unroll
  for (int dk = 0; dk < 2; ++dk) {
    int kx = k1 + 16 * dk;
    int num = x + kx - 23;
    if (num >= 0) {
      int qq = num >> 4;
      if (qq < 16) {
        #pragma unroll
        for (int ky = 0; ky < 3; ++ky) {
          int hh = h + ky - 1;
          if (hh >= 0 && hh < 128)
            acc += c[hh * 16 + qq] * w[(2 - ky) * 32 + (31 - kx)];
        }
      }
    }
  }
  acc += up_b[0];
  u1[h * 256 + x] = acc > 0.f ? acc : 0.4f * acc;
}

// ---------------- upsample stage 2: u1[128][256] -> cu[128][4096] bf16 ----------------
__global__ __launch_bounds__(256) void upsample2_kernel(
    const float* __restrict__ u1, const float* __restrict__ up_w,
    const float* __restrict__ up_b, unsigned short* __restrict__ cu)
{
  int x = blockIdx.x * 256 + threadIdx.x;  // 0..4095
  int h = blockIdx.y;                      // 0..127
  const float* w = up_w + 96;              // stage 1 kernel
  float acc = 0.f;
  int k1 = (23 - x) & 15;
  #pragma unroll
  for (int dk = 0; dk < 2; ++dk) {
    int kx = k1 + 16 * dk;
    int num = x + kx - 23;
    if (num >= 0) {
      int qq = num >> 4;
      if (qq < 256) {
        #pragma unroll
        for (int ky = 0; ky < 3; ++ky) {
          int hh = h + ky - 1;
          if (hh >= 0 && hh < 128)
            acc += u1[hh * 256 + qq] * w[(2 - ky) * 32 + (31 - kx)];
        }
      }
    }
  }
  acc += up_b[1];
  acc = acc > 0.f ? acc : 0.4f * acc;
  cu[(size_t)h * TLEN + x] = f2bf(acc);
}

// ---------------- front causal conv: x[4096] -> h[512][4096] ----------------
__global__ __launch_bounds__(256) void front_kernel(
    const float* __restrict__ x, const float* __restrict__ fw, const float* __restrict__ fb,
    float* __restrict__ hf, unsigned short* __restrict__ hbf)
{
  __shared__ float xs[287];
  int tid = threadIdx.x;
  int tb = blockIdx.x * 256;
  int o = blockIdx.y;
  for (int j = tid; j < 287; j += 256) {
    int gx = tb - 31 + j;
    xs[j] = (gx >= 0) ? x[gx] : 0.f;
  }
  __syncthreads();
  float acc = 0.f;
  const float* wo = fw + o * 32;
  #pragma unroll
  for (int k = 0; k < 32; ++k) acc += wo[k] * xs[tid + k];
  acc += fb[o];
  acc = acc > 0.f ? acc : 0.f;
  int t = tb + tid;
  hf[(size_t)o * TLEN + t] = acc;
  hbf[(size_t)o * HSTRIDE + HPAD + t] = f2bf(acc);
}

// ---------------- layer kernel A: o = tanh(f)*sigmoid(g) ----------------
// f = Wf0 @ h(t-d) + Wf1 @ h(t) + CF @ cu + fb + cfb   (g likewise)
__global__ __launch_bounds__(256) void gemm_a_kernel(
    const float* __restrict__ Wf, const float* __restrict__ Wg,
    const float* __restrict__ CF, const float* __restrict__ CG,
    const float* __restrict__ fb, const float* __restrict__ gb,
    const float* __restrict__ cfb, const float* __restrict__ cgb,
    const unsigned short* __restrict__ hbf, const unsigned short* __restrict__ cu,
    unsigned short* __restrict__ obf, const int d)
{
  __shared__ __align__(16) unsigned short As[4][64][40];  // Wf0,Wf1,Wg0,Wg1 tiles [o][i]
  __shared__ __align__(16) unsigned short Xs[2][4][64][8]; // taps: [kgrp][t][k&7]

  const int tid = threadIdx.x;
  const int n0 = blockIdx.x * 64;
  const int m0 = blockIdx.y * 64;
  const int lane = tid & 63;
  const int wave = tid >> 6;
  const int wm = (wave >> 1) * 32;
  const int wn = (wave & 1) * 32;
  const int lm = lane & 15;
  const int qd = lane >> 4;

  floatx4 accF[2][2], accG[2][2];
  #pragma unroll
  for (int a = 0; a < 2; ++a)
    #pragma unroll
    for (int b = 0; b < 2; ++b) {
      accF[a][b] = (floatx4){0.f, 0.f, 0.f, 0.f};
      accG[a][b] = (floatx4){0.f, 0.f, 0.f, 0.f};
    }

  // ---- conv phase: K=512 in 16 steps, both taps per step ----
  for (int kk = 0; kk < 16; ++kk) {
    const int k0 = kk * 32;
    #pragma unroll
    for (int j = 0; j < 8; ++j) {
      int p = tid + j * 256;        // 64x32 (o,i) pairs
      int o = p >> 5, i = p & 31;
      float2 wf = *(const float2*)&Wf[((size_t)(m0 + o) * RCH + (k0 + i)) * 2];
      float2 wg = *(const float2*)&Wg[((size_t)(m0 + o) * RCH + (k0 + i)) * 2];
      As[0][o][i] = f2bf(wf.x);
      As[1][o][i] = f2bf(wf.y);
      As[2][o][i] = f2bf(wg.x);
      As[3][o][i] = f2bf(wg.y);
    }
    #pragma unroll
    for (int j = 0; j < 8; ++j) {
      int p = tid + j * 256;        // 32x64 (k,t)
      int k = p >> 6, t = p & 63;
      const unsigned short* hp = hbf + (size_t)(k0 + k) * HSTRIDE + HPAD + n0 + t;
      Xs[0][k >> 3][t][k & 7] = hp[-d];
      Xs[1][k >> 3][t][k & 7] = hp[0];
    }
    __syncthreads();

    short8 af[4][2];
    #pragma unroll
    for (int s = 0; s < 4; ++s)
      #pragma unroll
      for (int mt = 0; mt < 2; ++mt)
        af[s][mt] = *(const short8*)&As[s][wm + mt * 16 + lm][qd * 8];
    short8 xf[2][2];
    #pragma unroll
    for (int tp = 0; tp < 2; ++tp)
      #pragma unroll
      for (int nt = 0; nt < 2; ++nt)
        xf[tp][nt] = *(const short8*)&Xs[tp][qd][wn + nt * 16 + lm][0];
    #pragma unroll
    for (int mt = 0; mt < 2; ++mt)
      #pragma unroll
      for (int nt = 0; nt < 2; ++nt) {
        accF[mt][nt] = MFMA_BF16(af[0][mt], xf[0][nt], accF[mt][nt]);
        accF[mt][nt] = MFMA_BF16(af[1][mt], xf[1][nt], accF[mt][nt]);
        accG[mt][nt] = MFMA_BF16(af[2][mt], xf[0][nt], accG[mt][nt]);
        accG[mt][nt] = MFMA_BF16(af[3][mt], xf[1][nt], accG[mt][nt]);
      }
    __syncthreads();
  }

  // ---- cond phase: K=128 in 4 steps ----
  for (int kk = 0; kk < 4; ++kk) {
    const int k0 = kk * 32;
    #pragma unroll
    for (int j = 0; j < 8; ++j) {
      int p = tid + j * 256;
      int o = p >> 5, i = p & 31;
      As[0][o][i] = f2bf(CF[(size_t)(m0 + o) * CINCH + k0 + i]);
      As[2][o][i] = f2bf(CG[(size_t)(m0 + o) * CINCH + k0 + i]);
    }
    #pragma unroll
    for (int j = 0; j < 8; ++j) {
      int p = tid + j * 256;
      int k = p >> 6, t = p & 63;
      Xs[0][k >> 3][t][k & 7] = cu[(size_t)(k0 + k) * TLEN + n0 + t];
    }
    __syncthreads();
    short8 af0[2], af2[2], xf[2];
    #pragma unroll
    for (int mt = 0; mt < 2; ++mt) {
      af0[mt] = *(const short8*)&As[0][wm + mt * 16 + lm][qd * 8];
      af2[mt] = *(const short8*)&As[2][wm + mt * 16 + lm][qd * 8];
    }
    #pragma unroll
    for (int nt = 0; nt < 2; ++nt)
      xf[nt] = *(const short8*)&Xs[0][qd][wn + nt * 16 + lm][0];
    #pragma unroll
    for (int mt = 0; mt < 2; ++mt)
      #pragma unroll
      for (int nt = 0; nt < 2; ++nt) {
        accF[mt][nt] = MFMA_BF16(af0[mt], xf[nt], accF[mt][nt]);
        accG[mt][nt] = MFMA_BF16(af2[mt], xf[nt], accG[mt][nt]);
      }
    __syncthreads();
  }

  // ---- epilogue: o = tanh(f)*sigmoid(g) -> bf16 ----
  #pragma unroll
  for (int mt = 0; mt < 2; ++mt)
    #pragma unroll
    for (int nt = 0; nt < 2; ++nt) {
      int t = n0 + wn + nt * 16 + lm;
      #pragma unroll
      for (int r = 0; r < 4; ++r) {
        int oc = m0 + wm + mt * 16 + qd * 4 + r;
        float f = accF[mt][nt][r] + fb[oc] + cfb[oc];
        float g = accG[mt][nt][r] + gb[oc] + cgb[oc];
        float ef = __expf(-2.f * f);
        float th = (1.f - ef) / (1.f + ef);
        float sg = 1.f / (1.f + __expf(-g));
        obf[(size_t)oc * TLEN + t] = f2bf(th * sg);
      }
    }
}

// ---------------- layer kernel B: h=(h+res)*sqrt_half; skip+=skipproj ----------------
__global__ __launch_bounds__(256) void gemm_b_kernel(
    const float* __restrict__ Wr, const float* __restrict__ Wsk,
    const float* __restrict__ rb, const float* __restrict__ sb,
    const unsigned short* __restrict__ obf,
    float* __restrict__ hf, unsigned short* __restrict__ hbf,
    float* __restrict__ skip, const int first)
{
  __shared__ __align__(16) unsigned short As[2][64][40];
  __shared__ __align__(16) unsigned short Xs[4][64][8];

  const int tid = threadIdx.x;
  const int n0 = blockIdx.x * 64;
  const int m0 = blockIdx.y * 64;
  const int lane = tid & 63;
  const int wave = tid >> 6;
  const int wm = (wave >> 1) * 32;
  const int wn = (wave & 1) * 32;
  const int lm = lane & 15;
  const int qd = lane >> 4;

  floatx4 accR[2][2], accS[2][2];
  #pragma unroll
  for (int a = 0; a < 2; ++a)
    #pragma unroll
    for (int b = 0; b < 2; ++b) {
      accR[a][b] = (floatx4){0.f, 0.f, 0.f, 0.f};
      accS[a][b] = (floatx4){0.f, 0.f, 0.f, 0.f};
    }

  for (int kk = 0; kk < 16; ++kk) {
    const int k0 = kk * 32;
    #pragma unroll
    for (int j = 0; j < 2; ++j) {
      int p = tid + j * 256;        // 64 rows x 8 float4
      int o = p >> 3, i4 = (p & 7) * 4;
      float4 wr = *(const float4*)&Wr[(size_t)(m0 + o) * GCH + k0 + i4];
      float4 wk = *(const float4*)&Wsk[(size_t)(m0 + o) * GCH + k0 + i4];
      As[0][o][i4 + 0] = f2bf(wr.x); As[0][o][i4 + 1] = f2bf(wr.y);
      As[0][o][i4 + 2] = f2bf(wr.z); As[0][o][i4 + 3] = f2bf(wr.w);
      As[1][o][i4 + 0] = f2bf(wk.x); As[1][o][i4 + 1] = f2bf(wk.y);
      As[1][o][i4 + 2] = f2bf(wk.z); As[1][o][i4 + 3] = f2bf(wk.w);
    }
    #pragma unroll
    for (int j = 0; j < 8; ++j) {
      int p = tid + j * 256;
      int k = p >> 6, t = p & 63;
      Xs[k >> 3][t][k & 7] = obf[(size_t)(k0 + k) * TLEN + n0 + t];
    }
    __syncthreads();

    short8 ar[2], ak[2], xf[2];
    #pragma unroll
    for (int mt = 0; mt < 2; ++mt) {
      ar[mt] = *(const short8*)&As[0][wm + mt * 16 + lm][qd * 8];
      ak[mt] = *(const short8*)&As[1][wm + mt * 16 + lm][qd * 8];
    }
    #pragma unroll
    for (int nt = 0; nt < 2; ++nt)
      xf[nt] = *(const short8*)&Xs[qd][wn + nt * 16 + lm][0];
    #pragma unroll
    for (int mt = 0; mt < 2; ++mt)
      #pragma unroll
      for (int nt = 0; nt < 2; ++nt) {
        accR[mt][nt] = MFMA_BF16(ar[mt], xf[nt], accR[mt][nt]);
        accS[mt][nt] = MFMA_BF16(ak[mt], xf[nt], accS[mt][nt]);
      }
    __syncthreads();
  }

  #pragma unroll
  for (int mt = 0; mt < 2; ++mt)
    #pragma unroll
    for (int nt = 0; nt < 2; ++nt) {
      int t = n0 + wn + nt * 16 + lm;
      #pragma unroll
      for (int r = 0; r < 4; ++r) {
        int oc = m0 + wm + mt * 16 + qd * 4 + r;
        size_t idx = (size_t)oc * TLEN + t;
        float hv = (hf[idx] + accR[mt][nt][r] + rb[oc]) * SQRT_HALF;
        hf[idx] = hv;
        hbf[(size_t)oc * HSTRIDE + HPAD + t] = f2bf(hv);
        float sv = accS[mt][nt][r] + sb[oc];
        skip[idx] = first ? sv : (skip[idx] + sv);
      }
    }
}

// ---------------- final1: t1 = relu(fin1 @ relu(skip) + b1) ----------------
__global__ __launch_bounds__(256) void final1_kernel(
    const float* __restrict__ W1, const float* __restrict__ b1,
    const float* __restrict__ skip, unsigned short* __restrict__ t1)
{
  __shared__ __align__(16) unsigned short As[64][40];
  __shared__ __align__(16) unsigned short Xs[4][64][8];

  const int tid = threadIdx.x;
  const int n0 = blockIdx.x * 64;
  const int m0 = blockIdx.y * 64;
  const int lane = tid & 63;
  const int wave = tid >> 6;
  const int wm = (wave >> 1) * 32;
  const int wn = (wave & 1) * 32;
  const int lm = lane & 15;
  const int qd = lane >> 4;

  floatx4 acc[2][2];
  #pragma unroll
  for (int a = 0; a < 2; ++a)
    #pragma unroll
    for (int b = 0; b < 2; ++b) acc[a][b] = (floatx4){0.f, 0.f, 0.f, 0.f};

  for (int kk = 0; kk < 16; ++kk) {
    const int k0 = kk * 32;
    #pragma unroll
    for (int j = 0; j < 1; ++j) {
      int p = tid;                  // 64 rows x 8 float4 = 512 -> 2 per thread
      int o = p >> 3, i4 = (p & 7) * 4;
      float4 w0 = *(const float4*)&W1[(size_t)(m0 + o) * SCH + k0 + i4];
      As[o][i4 + 0] = f2bf(w0.x); As[o][i4 + 1] = f2bf(w0.y);
      As[o][i4 + 2] = f2bf(w0.z); As[o][i4 + 3] = f2bf(w0.w);
      int p2 = tid + 256;
      int o2 = p2 >> 3, j4 = (p2 & 7) * 4;
      float4 w1 = *(const float4*)&W1[(size_t)(m0 + o2) * SCH + k0 + j4];
      As[o2][j4 + 0] = f2bf(w1.x); As[o2][j4 + 1] = f2bf(w1.y);
      As[o2][j4 + 2] = f2bf(w1.z); As[o2][j4 + 3] = f2bf(w1.w);
    }
    #pragma unroll
    for (int j = 0; j < 8; ++j) {
      int p = tid + j * 256;
      int k = p >> 6, t = p & 63;
      float v = skip[(size_t)(k0 + k) * TLEN + n0 + t];
      Xs[k >> 3][t][k & 7] = f2bf(v > 0.f ? v : 0.f);
    }
    __syncthreads();

    short8 aw[2], xf[2];
    #pragma unroll
    for (int mt = 0; mt < 2; ++mt)
      aw[mt] = *(const short8*)&As[wm + mt * 16 + lm][qd * 8];
    #pragma unroll
    for (int nt = 0; nt < 2; ++nt)
      xf[nt] = *(const short8*)&Xs[qd][wn + nt * 16 + lm][0];
    #pragma unroll
    for (int mt = 0; mt < 2; ++mt)
      #pragma unroll
      for (int nt = 0; nt < 2; ++nt)
        acc[mt][nt] = MFMA_BF16(aw[mt], xf[nt], acc[mt][nt]);
    __syncthreads();
  }

  #pragma unroll
  for (int mt = 0; mt < 2; ++mt)
    #pragma unroll
    for (int nt = 0; nt < 2; ++nt) {
      int t = n0 + wn + nt * 16 + lm;
      #pragma unroll
      for (int r = 0; r < 4; ++r) {
        int oc = m0 + wm + mt * 16 + qd * 4 + r;
        float v = acc[mt][nt][r] + b1[oc];
        t1[(size_t)oc * TLEN + t] = f2bf(v > 0.f ? v : 0.f);
      }
    }
}

// ---------------- final2: out[2][4096] = fin2 @ t1 + b2 ----------------
__global__ __launch_bounds__(256) void final2_kernel(
    const float* __restrict__ W2, const float* __restrict__ b2,
    const unsigned short* __restrict__ t1, float* __restrict__ out)
{
  int t = blockIdx.x * 256 + threadIdx.x;  // 0..4095
  float a0 = 0.f, a1 = 0.f;
  for (int i = 0; i < 512; ++i) {
    float v = bf2f(t1[(size_t)i * TLEN + t]);
    a0 += W2[i] * v;
    a1 += W2[512 + i] * v;
  }
  out[t] = a0 + b2[0];
  out[TLEN + t] = a1 + b2[1];
}

extern "C" void kernel_launch(void* const* d_in, const int* in_sizes, int n_in,
                              void* d_out, int out_size, void* d_ws, size_t ws_size,
                              hipStream_t stream) {
  (void)in_sizes; (void)n_in; (void)out_size; (void)ws_size;
  const float* x       = (const float*)d_in[0];
  const float* c       = (const float*)d_in[1];
  const float* front_w = (const float*)d_in[2];
  const float* front_b = (const float*)d_in[3];
  const float* filt_w  = (const float*)d_in[4];
  const float* filt_b  = (const float*)d_in[5];
  const float* gate_w  = (const float*)d_in[6];
  const float* gate_b  = (const float*)d_in[7];
  const float* cf_w    = (const float*)d_in[8];
  const float* cf_b    = (const float*)d_in[9];
  const float* cg_w    = (const float*)d_in[10];
  const float* cg_b    = (const float*)d_in[11];
  const float* res_w   = (const float*)d_in[12];
  const float* res_b   = (const float*)d_in[13];
  const float* skip_w  = (const float*)d_in[14];
  const float* skip_b  = (const float*)d_in[15];
  const float* fin1_w  = (const float*)d_in[16];
  const float* fin1_b  = (const float*)d_in[17];
  const float* fin2_w  = (const float*)d_in[18];
  const float* fin2_b  = (const float*)d_in[19];
  const float* up_w    = (const float*)d_in[20];
  const float* up_b    = (const float*)d_in[21];

  char* ws = (char*)d_ws;
  float* u1            = (float*)ws;           ws += (size_t)128 * 256 * 4;
  unsigned short* cu   = (unsigned short*)ws;  ws += (size_t)128 * TLEN * 2;
  float* hf            = (float*)ws;           ws += (size_t)512 * TLEN * 4;
  unsigned short* hbf  = (unsigned short*)ws;  ws += (size_t)512 * HSTRIDE * 2;
  unsigned short* obf  = (unsigned short*)ws;  ws += (size_t)512 * TLEN * 2;
  float* skip          = (float*)ws;           ws += (size_t)512 * TLEN * 4;
  unsigned short* t1   = (unsigned short*)ws;  ws += (size_t)512 * TLEN * 2;
  float* out           = (float*)d_out;

  // zero the padded bf16 h buffer (left-pad columns must read as 0 for t < d)
  hipMemsetAsync(hbf, 0, (size_t)512 * HSTRIDE * 2, stream);

  upsample1_kernel<<<dim3(128), 256, 0, stream>>>(c, up_w, up_b, u1);
  upsample2_kernel<<<dim3(16, 128), 256, 0, stream>>>(u1, up_w, up_b, cu);
  front_kernel<<<dim3(16, 512), 256, 0, stream>>>(x, front_w, front_b, hf, hbf);

  for (int l = 0; l < 30; ++l) {
    int d = 1 << (l % 10);
    gemm_a_kernel<<<dim3(64, 8), 256, 0, stream>>>(
        filt_w + (size_t)l * GCH * RCH * 2, gate_w + (size_t)l * GCH * RCH * 2,
        cf_w + (size_t)l * GCH * CINCH, cg_w + (size_t)l * GCH * CINCH,
        filt_b + (size_t)l * GCH, gate_b + (size_t)l * GCH,
        cf_b + (size_t)l * GCH, cg_b + (size_t)l * GCH,
        hbf, cu, obf, d);
    gemm_b_kernel<<<dim3(64, 8), 256, 0, stream>>>(
        res_w + (size_t)l * RCH * GCH, skip_w + (size_t)l * SCH * GCH,
        res_b + (size_t)l * RCH, skip_b + (size_t)l * SCH,
        obf, hf, hbf, skip, (l == 0) ? 1 : 0);
  }

  final1_kernel<<<dim3(64, 8), 256, 0, stream>>>(fin1_w, fin1_b, skip, t1);
  final2_kernel<<<dim3(16), 256, 0, stream>>>(fin2_w, fin2_b, t1, out);
}

// Round 2
// 2132.389 us; speedup vs baseline: 1.0876x; 1.0876x over previous
//
#include <hip/hip_runtime.h>
#include <hip/hip_bf16.h>

#define TLEN 4096
#define HPADT 512
#define SQRT_HALF 0.70710678118654752f

typedef __attribute__((ext_vector_type(8))) short short8;
typedef __attribute__((ext_vector_type(4))) float floatx4;
typedef __attribute__((ext_vector_type(4))) unsigned short ushort4v;

#define MFMA_BF16(a, b, c) __builtin_amdgcn_mfma_f32_16x16x32_bf16((a), (b), (c), 0, 0, 0)

__device__ __forceinline__ float bf2f(unsigned short u) {
  union { unsigned int i; float f; } v; v.i = ((unsigned int)u) << 16; return v.f;
}
__device__ __forceinline__ unsigned short f2bf(float x) {
  union { float f; unsigned int i; } v; v.f = x;
  unsigned int r = v.i + 0x7FFFu + ((v.i >> 16) & 1u);
  return (unsigned short)(r >> 16);
}
__device__ __forceinline__ short8 ld8(const unsigned short* p) {
  return *(const short8*)p;
}

// ============ weight pre-cast kernels (run once per call) ============

// filt_w/gate_w [30][512][512][2] fp32 -> Wc [30][4][512][512] bf16 (taps split)
__global__ __launch_bounds__(256) void cast_conv_kernel(
    const float* __restrict__ fw, const float* __restrict__ gw,
    unsigned short* __restrict__ out)
{
  size_t idx = (size_t)blockIdx.x * 256 + threadIdx.x;   // (l,o,i)
  float2 f = *(const float2*)&fw[idx * 2];
  float2 g = *(const float2*)&gw[idx * 2];
  size_t l = idx >> 18;
  size_t ok = idx & 262143;
  size_t base = l * 4 * 262144 + ok;
  out[base + 0 * 262144] = f2bf(f.x);
  out[base + 1 * 262144] = f2bf(f.y);
  out[base + 2 * 262144] = f2bf(g.x);
  out[base + 3 * 262144] = f2bf(g.y);
}

// res_w/skip_w [30][512][512] fp32 -> RSc [30][2][512][512] bf16
__global__ __launch_bounds__(256) void cast_rs_kernel(
    const float* __restrict__ rw, const float* __restrict__ sw,
    unsigned short* __restrict__ out)
{
  size_t idx = (size_t)blockIdx.x * 256 + threadIdx.x;
  size_t l = idx >> 18;
  size_t ok = idx & 262143;
  out[l * 2 * 262144 + ok] = f2bf(rw[idx]);
  out[(l * 2 + 1) * 262144 + ok] = f2bf(sw[idx]);
}

// cf_w/cg_w [30][512][128] fp32 -> Cc [30][2][512][128] bf16
__global__ __launch_bounds__(256) void cast_cond_kernel(
    const float* __restrict__ cf, const float* __restrict__ cg,
    unsigned short* __restrict__ out)
{
  size_t idx = (size_t)blockIdx.x * 256 + threadIdx.x;
  size_t l = idx >> 16;
  size_t ok = idx & 65535;
  out[l * 2 * 65536 + ok] = f2bf(cf[idx]);
  out[(l * 2 + 1) * 65536 + ok] = f2bf(cg[idx]);
}

__global__ __launch_bounds__(256) void cast_f1_kernel(
    const float* __restrict__ w, unsigned short* __restrict__ out)
{
  size_t idx = (size_t)blockIdx.x * 256 + threadIdx.x;
  out[idx] = f2bf(w[idx]);
}

// combined biases: fgb = filt_b + cf_b ; ggb = gate_b + cg_b   [30][512]
__global__ __launch_bounds__(256) void cast_bias_kernel(
    const float* __restrict__ fb, const float* __restrict__ cfb,
    const float* __restrict__ gb, const float* __restrict__ cgb,
    float* __restrict__ fgb, float* __restrict__ ggb)
{
  size_t idx = (size_t)blockIdx.x * 256 + threadIdx.x;
  fgb[idx] = fb[idx] + cfb[idx];
  ggb[idx] = gb[idx] + cgb[idx];
}

// ============ upsample ============

__global__ __launch_bounds__(256) void upsample1_kernel(
    const float* __restrict__ c, const float* __restrict__ up_w,
    const float* __restrict__ up_b, float* __restrict__ u1)
{
  int x = threadIdx.x;
  int h = blockIdx.x;
  const float* w = up_w;
  float acc = 0.f;
  int k1 = (23 - x) & 15;
  #pragma unroll
  for (int dk = 0; dk < 2; ++dk) {
    int kx = k1 + 16 * dk;
    int num = x + kx - 23;
    if (num >= 0) {
      int qq = num >> 4;
      if (qq < 16) {
        #pragma unroll
        for (int ky = 0; ky < 3; ++ky) {
          int hh = h + ky - 1;
          if (hh >= 0 && hh < 128)
            acc += c[hh * 16 + qq] * w[(2 - ky) * 32 + (31 - kx)];
        }
      }
    }
  }
  acc += up_b[0];
  u1[h * 256 + x] = acc > 0.f ? acc : 0.4f * acc;
}

// -> cu[t][128] bf16 (t-major)
__global__ __launch_bounds__(256) void upsample2_kernel(
    const float* __restrict__ u1, const float* __restrict__ up_w,
    const float* __restrict__ up_b, unsigned short* __restrict__ cu)
{
  int x = blockIdx.x * 256 + threadIdx.x;
  int h = blockIdx.y;
  const float* w = up_w + 96;
  float acc = 0.f;
  int k1 = (23 - x) & 15;
  #pragma unroll
  for (int dk = 0; dk < 2; ++dk) {
    int kx = k1 + 16 * dk;
    int num = x + kx - 23;
    if (num >= 0) {
      int qq = num >> 4;
      if (qq < 256) {
        #pragma unroll
        for (int ky = 0; ky < 3; ++ky) {
          int hh = h + ky - 1;
          if (hh >= 0 && hh < 128)
            acc += u1[hh * 256 + qq] * w[(2 - ky) * 32 + (31 - kx)];
        }
      }
    }
  }
  acc += up_b[1];
  acc = acc > 0.f ? acc : 0.4f * acc;
  cu[(size_t)x * 128 + h] = f2bf(acc);
}

// ============ front conv -> h[t][512] (fp32 + bf16 padded) ============
__global__ __launch_bounds__(256) void front_kernel(
    const float* __restrict__ x, const float* __restrict__ fw, const float* __restrict__ fb,
    float* __restrict__ hf, unsigned short* __restrict__ hbf)
{
  __shared__ float xs[40];
  int tid = threadIdx.x;
  int o = blockIdx.y * 256 + tid;
  int t0 = blockIdx.x * 8;
  if (tid < 39) {
    int gx = t0 - 31 + tid;
    xs[tid] = (gx >= 0) ? x[gx] : 0.f;
  }
  __syncthreads();
  float w[32];
  #pragma unroll
  for (int k = 0; k < 32; ++k) w[k] = fw[o * 32 + k];
  float b = fb[o];
  #pragma unroll
  for (int j = 0; j < 8; ++j) {
    float acc = b;
    #pragma unroll
    for (int k = 0; k < 32; ++k) acc += w[k] * xs[j + k];
    acc = acc > 0.f ? acc : 0.f;
    int t = t0 + j;
    hf[(size_t)t * 512 + o] = acc;
    hbf[(size_t)(HPADT + t) * 512 + o] = f2bf(acc);
  }
}

// ============ layer kernel A: o = tanh(f)*sigmoid(g) ============
// LDS-free: direct 16B fragment loads from bf16 global, no barriers.
// wave tile 32o x 64t; block = 4 waves (2m x 2n) = 64o x 128t; grid 32x8 = 256 blocks.
__global__ __launch_bounds__(256) void gemm_a_kernel(
    const unsigned short* __restrict__ W,    // [4][512][512] bf16: Wf0,Wf1,Wg0,Wg1
    const unsigned short* __restrict__ C,    // [2][512][128] bf16: CF,CG
    const float* __restrict__ fgb, const float* __restrict__ ggb,
    const unsigned short* __restrict__ hbf,  // [(HPADT+T)][512]
    const unsigned short* __restrict__ cu,   // [T][128]
    unsigned short* __restrict__ obf,        // [T][512]
    const int d)
{
  const int tid = threadIdx.x;
  const int lane = tid & 63, wave = tid >> 6;
  const int lm = lane & 15, qd = lane >> 4;
  const int n0 = blockIdx.x * 128 + (wave >> 1) * 64;
  const int m0 = blockIdx.y * 64 + (wave & 1) * 32;

  floatx4 accF[2][4], accG[2][4];
  #pragma unroll
  for (int a = 0; a < 2; ++a)
    #pragma unroll
    for (int b = 0; b < 4; ++b) {
      accF[a][b] = (floatx4){0.f, 0.f, 0.f, 0.f};
      accG[a][b] = (floatx4){0.f, 0.f, 0.f, 0.f};
    }

  const unsigned short* arow[2];
  #pragma unroll
  for (int mt = 0; mt < 2; ++mt)
    arow[mt] = W + (((size_t)(m0 + mt * 16 + lm)) << 9) + qd * 8;
  const unsigned short* xrow[4];
  #pragma unroll
  for (int nt = 0; nt < 4; ++nt)
    xrow[nt] = hbf + (((size_t)(HPADT + n0 + nt * 16 + lm)) << 9) + qd * 8;
  const int doff = d << 9;

  #pragma unroll 4
  for (int k0 = 0; k0 < 512; k0 += 32) {
    short8 A0[2], A1[2], A2[2], A3[2], X0[4], X1[4];
    #pragma unroll
    for (int mt = 0; mt < 2; ++mt) {
      A0[mt] = ld8(arow[mt] + k0);
      A1[mt] = ld8(arow[mt] + 262144 + k0);
      A2[mt] = ld8(arow[mt] + 2 * 262144 + k0);
      A3[mt] = ld8(arow[mt] + 3 * 262144 + k0);
    }
    #pragma unroll
    for (int nt = 0; nt < 4; ++nt) {
      X0[nt] = ld8(xrow[nt] - doff + k0);
      X1[nt] = ld8(xrow[nt] + k0);
    }
    #pragma unroll
    for (int mt = 0; mt < 2; ++mt)
      #pragma unroll
      for (int nt = 0; nt < 4; ++nt) {
        accF[mt][nt] = MFMA_BF16(A0[mt], X0[nt], accF[mt][nt]);
        accF[mt][nt] = MFMA_BF16(A1[mt], X1[nt], accF[mt][nt]);
        accG[mt][nt] = MFMA_BF16(A2[mt], X0[nt], accG[mt][nt]);
        accG[mt][nt] = MFMA_BF16(A3[mt], X1[nt], accG[mt][nt]);
      }
  }

  // cond phase K=128
  const unsigned short* crow[2];
  #pragma unroll
  for (int mt = 0; mt < 2; ++mt)
    crow[mt] = C + ((size_t)(m0 + mt * 16 + lm)) * 128 + qd * 8;
  const unsigned short* curow[4];
  #pragma unroll
  for (int nt = 0; nt < 4; ++nt)
    curow[nt] = cu + ((size_t)(n0 + nt * 16 + lm)) * 128 + qd * 8;

  #pragma unroll
  for (int k0 = 0; k0 < 128; k0 += 32) {
    short8 AF[2], AG[2], XC[4];
    #pragma unroll
    for (int mt = 0; mt < 2; ++mt) {
      AF[mt] = ld8(crow[mt] + k0);
      AG[mt] = ld8(crow[mt] + 65536 + k0);
    }
    #pragma unroll
    for (int nt = 0; nt < 4; ++nt) XC[nt] = ld8(curow[nt] + k0);
    #pragma unroll
    for (int mt = 0; mt < 2; ++mt)
      #pragma unroll
      for (int nt = 0; nt < 4; ++nt) {
        accF[mt][nt] = MFMA_BF16(AF[mt], XC[nt], accF[mt][nt]);
        accG[mt][nt] = MFMA_BF16(AG[mt], XC[nt], accG[mt][nt]);
      }
  }

  // epilogue
  #pragma unroll
  for (int mt = 0; mt < 2; ++mt) {
    int oc0 = m0 + mt * 16 + qd * 4;
    floatx4 fb4 = *(const floatx4*)&fgb[oc0];
    floatx4 gb4 = *(const floatx4*)&ggb[oc0];
    #pragma unroll
    for (int nt = 0; nt < 4; ++nt) {
      int t = n0 + nt * 16 + lm;
      ushort4v o4;
      #pragma unroll
      for (int r = 0; r < 4; ++r) {
        float f = accF[mt][nt][r] + fb4[r];
        float g = accG[mt][nt][r] + gb4[r];
        float ef = __expf(-2.f * f);
        float th = (1.f - ef) / (1.f + ef);
        float sg = 1.f / (1.f + __expf(-g));
        o4[r] = f2bf(th * sg);
      }
      *(ushort4v*)&obf[(size_t)t * 512 + oc0] = o4;
    }
  }
}

// ============ layer kernel B: h=(h+res)*sqrt_half; skip+=skipproj ============
__global__ __launch_bounds__(256) void gemm_b_kernel(
    const unsigned short* __restrict__ RS,   // [2][512][512] bf16: Wres, Wskip
    const float* __restrict__ rb, const float* __restrict__ sb,
    const unsigned short* __restrict__ obf,  // [T][512]
    float* __restrict__ hf, unsigned short* __restrict__ hbf,
    float* __restrict__ skip, unsigned short* __restrict__ skipbf,
    const int first, const int last)
{
  const int tid = threadIdx.x;
  const int lane = tid & 63, wave = tid >> 6;
  const int lm = lane & 15, qd = lane >> 4;
  const int n0 = blockIdx.x * 128 + (wave >> 1) * 64;
  const int m0 = blockIdx.y * 64 + (wave & 1) * 32;

  floatx4 accR[2][4], accS[2][4];
  #pragma unroll
  for (int a = 0; a < 2; ++a)
    #pragma unroll
    for (int b = 0; b < 4; ++b) {
      accR[a][b] = (floatx4){0.f, 0.f, 0.f, 0.f};
      accS[a][b] = (floatx4){0.f, 0.f, 0.f, 0.f};
    }

  const unsigned short* arow[2];
  #pragma unroll
  for (int mt = 0; mt < 2; ++mt)
    arow[mt] = RS + (((size_t)(m0 + mt * 16 + lm)) << 9) + qd * 8;
  const unsigned short* xrow[4];
  #pragma unroll
  for (int nt = 0; nt < 4; ++nt)
    xrow[nt] = obf + (((size_t)(n0 + nt * 16 + lm)) << 9) + qd * 8;

  #pragma unroll 4
  for (int k0 = 0; k0 < 512; k0 += 32) {
    short8 AR[2], AS[2], X[4];
    #pragma unroll
    for (int mt = 0; mt < 2; ++mt) {
      AR[mt] = ld8(arow[mt] + k0);
      AS[mt] = ld8(arow[mt] + 262144 + k0);
    }
    #pragma unroll
    for (int nt = 0; nt < 4; ++nt) X[nt] = ld8(xrow[nt] + k0);
    #pragma unroll
    for (int mt = 0; mt < 2; ++mt)
      #pragma unroll
      for (int nt = 0; nt < 4; ++nt) {
        accR[mt][nt] = MFMA_BF16(AR[mt], X[nt], accR[mt][nt]);
        accS[mt][nt] = MFMA_BF16(AS[mt], X[nt], accS[mt][nt]);
      }
  }

  #pragma unroll
  for (int mt = 0; mt < 2; ++mt) {
    int oc0 = m0 + mt * 16 + qd * 4;
    floatx4 rb4 = *(const floatx4*)&rb[oc0];
    floatx4 sb4 = *(const floatx4*)&sb[oc0];
    #pragma unroll
    for (int nt = 0; nt < 4; ++nt) {
      int t = n0 + nt * 16 + lm;
      size_t base = (size_t)t * 512 + oc0;
      floatx4 h4 = *(const floatx4*)&hf[base];
      floatx4 s4;
      if (first) s4 = (floatx4){0.f, 0.f, 0.f, 0.f};
      else s4 = *(const floatx4*)&skip[base];
      ushort4v hb4;
      #pragma unroll
      for (int r = 0; r < 4; ++r) {
        float hv = (h4[r] + accR[mt][nt][r] + rb4[r]) * SQRT_HALF;
        h4[r] = hv;
        hb4[r] = f2bf(hv);
        s4[r] = s4[r] + accS[mt][nt][r] + sb4[r];
      }
      *(floatx4*)&hf[base] = h4;
      *(ushort4v*)&hbf[(size_t)(HPADT + t) * 512 + oc0] = hb4;
      *(floatx4*)&skip[base] = s4;
      if (last) {
        ushort4v sk4;
        #pragma unroll
        for (int r = 0; r < 4; ++r) sk4[r] = f2bf(s4[r] > 0.f ? s4[r] : 0.f);
        *(ushort4v*)&skipbf[base] = sk4;
      }
    }
  }
}

// ============ final1: t1 = relu(W1 @ relu(skip) + b1) ============
__global__ __launch_bounds__(256) void final1_kernel(
    const unsigned short* __restrict__ W1,   // [512][512] bf16
    const float* __restrict__ b1,
    const unsigned short* __restrict__ skipbf,  // [T][512] bf16 (already relu'd)
    unsigned short* __restrict__ t1)
{
  const int tid = threadIdx.x;
  const int lane = tid & 63, wave = tid >> 6;
  const int lm = lane & 15, qd = lane >> 4;
  const int n0 = blockIdx.x * 128 + (wave >> 1) * 64;
  const int m0 = blockIdx.y * 64 + (wave & 1) * 32;

  floatx4 acc[2][4];
  #pragma unroll
  for (int a = 0; a < 2; ++a)
    #pragma unroll
    for (int b = 0; b < 4; ++b) acc[a][b] = (floatx4){0.f, 0.f, 0.f, 0.f};

  const unsigned short* arow[2];
  #pragma unroll
  for (int mt = 0; mt < 2; ++mt)
    arow[mt] = W1 + (((size_t)(m0 + mt * 16 + lm)) << 9) + qd * 8;
  const unsigned short* xrow[4];
  #pragma unroll
  for (int nt = 0; nt < 4; ++nt)
    xrow[nt] = skipbf + (((size_t)(n0 + nt * 16 + lm)) << 9) + qd * 8;

  #pragma unroll 4
  for (int k0 = 0; k0 < 512; k0 += 32) {
    short8 A[2], X[4];
    #pragma unroll
    for (int mt = 0; mt < 2; ++mt) A[mt] = ld8(arow[mt] + k0);
    #pragma unroll
    for (int nt = 0; nt < 4; ++nt) X[nt] = ld8(xrow[nt] + k0);
    #pragma unroll
    for (int mt = 0; mt < 2; ++mt)
      #pragma unroll
      for (int nt = 0; nt < 4; ++nt)
        acc[mt][nt] = MFMA_BF16(A[mt], X[nt], acc[mt][nt]);
  }

  #pragma unroll
  for (int mt = 0; mt < 2; ++mt) {
    int oc0 = m0 + mt * 16 + qd * 4;
    floatx4 b4 = *(const floatx4*)&b1[oc0];
    #pragma unroll
    for (int nt = 0; nt < 4; ++nt) {
      int t = n0 + nt * 16 + lm;
      ushort4v o4;
      #pragma unroll
      for (int r = 0; r < 4; ++r) {
        float v = acc[mt][nt][r] + b4[r];
        o4[r] = f2bf(v > 0.f ? v : 0.f);
      }
      *(ushort4v*)&t1[(size_t)t * 512 + oc0] = o4;
    }
  }
}

// ============ final2: out[2][T] = W2 @ t1 + b2 ============
__global__ __launch_bounds__(256) void final2_kernel(
    const float* __restrict__ W2, const float* __restrict__ b2,
    const unsigned short* __restrict__ t1, float* __restrict__ out)
{
  int t = blockIdx.x * 256 + threadIdx.x;
  const unsigned short* row = t1 + (size_t)t * 512;
  float a0 = 0.f, a1 = 0.f;
  for (int i = 0; i < 512; ++i) {
    float v = bf2f(row[i]);
    a0 += W2[i] * v;
    a1 += W2[512 + i] * v;
  }
  out[t] = a0 + b2[0];
  out[TLEN + t] = a1 + b2[1];
}

extern "C" void kernel_launch(void* const* d_in, const int* in_sizes, int n_in,
                              void* d_out, int out_size, void* d_ws, size_t ws_size,
                              hipStream_t stream) {
  (void)in_sizes; (void)n_in; (void)out_size; (void)ws_size;
  const float* x       = (const float*)d_in[0];
  const float* c       = (const float*)d_in[1];
  const float* front_w = (const float*)d_in[2];
  const float* front_b = (const float*)d_in[3];
  const float* filt_w  = (const float*)d_in[4];
  const float* filt_b  = (const float*)d_in[5];
  const float* gate_w  = (const float*)d_in[6];
  const float* gate_b  = (const float*)d_in[7];
  const float* cf_w    = (const float*)d_in[8];
  const float* cf_b    = (const float*)d_in[9];
  const float* cg_w    = (const float*)d_in[10];
  const float* cg_b    = (const float*)d_in[11];
  const float* res_w   = (const float*)d_in[12];
  const float* res_b   = (const float*)d_in[13];
  const float* skip_w  = (const float*)d_in[14];
  const float* skip_b  = (const float*)d_in[15];
  const float* fin1_w  = (const float*)d_in[16];
  const float* fin1_b  = (const float*)d_in[17];
  const float* fin2_w  = (const float*)d_in[18];
  const float* fin2_b  = (const float*)d_in[19];
  const float* up_w    = (const float*)d_in[20];
  const float* up_b    = (const float*)d_in[21];

  char* ws = (char*)d_ws;
  auto alloc = [&](size_t bytes) {
    char* p = ws;
    ws += (bytes + 255) & ~(size_t)255;
    return p;
  };
  unsigned short* Wc     = (unsigned short*)alloc((size_t)30 * 4 * 512 * 512 * 2);
  unsigned short* RSc    = (unsigned short*)alloc((size_t)30 * 2 * 512 * 512 * 2);
  unsigned short* Cc     = (unsigned short*)alloc((size_t)30 * 2 * 512 * 128 * 2);
  unsigned short* F1c    = (unsigned short*)alloc((size_t)512 * 512 * 2);
  float* fgb             = (float*)alloc((size_t)30 * 512 * 4);
  float* ggb             = (float*)alloc((size_t)30 * 512 * 4);
  float* u1              = (float*)alloc((size_t)128 * 256 * 4);
  unsigned short* cu     = (unsigned short*)alloc((size_t)TLEN * 128 * 2);
  float* hf              = (float*)alloc((size_t)TLEN * 512 * 4);
  unsigned short* hbf    = (unsigned short*)alloc((size_t)(HPADT + TLEN) * 512 * 2);
  unsigned short* obf    = (unsigned short*)alloc((size_t)TLEN * 512 * 2);
  float* skip            = (float*)alloc((size_t)TLEN * 512 * 4);
  unsigned short* skipbf = (unsigned short*)alloc((size_t)TLEN * 512 * 2);
  unsigned short* t1     = (unsigned short*)alloc((size_t)TLEN * 512 * 2);
  float* out             = (float*)d_out;

  // zero the left pad of the bf16 h buffer (tap t-d must read 0 for t<d)
  hipMemsetAsync(hbf, 0, (size_t)HPADT * 512 * 2, stream);

  cast_conv_kernel<<<30720, 256, 0, stream>>>(filt_w, gate_w, Wc);
  cast_rs_kernel<<<30720, 256, 0, stream>>>(res_w, skip_w, RSc);
  cast_cond_kernel<<<7680, 256, 0, stream>>>(cf_w, cg_w, Cc);
  cast_f1_kernel<<<1024, 256, 0, stream>>>(fin1_w, F1c);
  cast_bias_kernel<<<60, 256, 0, stream>>>(filt_b, cf_b, gate_b, cg_b, fgb, ggb);

  upsample1_kernel<<<dim3(128), 256, 0, stream>>>(c, up_w, up_b, u1);
  upsample2_kernel<<<dim3(16, 128), 256, 0, stream>>>(u1, up_w, up_b, cu);
  front_kernel<<<dim3(512, 2), 256, 0, stream>>>(x, front_w, front_b, hf, hbf);

  for (int l = 0; l < 30; ++l) {
    int d = 1 << (l % 10);
    gemm_a_kernel<<<dim3(32, 8), 256, 0, stream>>>(
        Wc + (size_t)l * 4 * 262144, Cc + (size_t)l * 2 * 65536,
        fgb + (size_t)l * 512, ggb + (size_t)l * 512,
        hbf, cu, obf, d);
    gemm_b_kernel<<<dim3(32, 8), 256, 0, stream>>>(
        RSc + (size_t)l * 2 * 262144,
        res_b + (size_t)l * 512, skip_b + (size_t)l * 512,
        obf, hf, hbf, skip, skipbf, (l == 0) ? 1 : 0, (l == 29) ? 1 : 0);
  }

  final1_kernel<<<dim3(32, 8), 256, 0, stream>>>(F1c, fin1_b, skipbf, t1);
  final2_kernel<<<16, 256, 0, stream>>>(fin2_w, fin2_b, t1, out);
}

// Round 3
// 1503.885 us; speedup vs baseline: 1.5421x; 1.4179x over previous
//
#include <hip/hip_runtime.h>
#include <hip/hip_bf16.h>

#define TLEN 4096
#define HPADT 512
#define SQRT_HALF 0.70710678118654752f

typedef __attribute__((ext_vector_type(8))) short short8;
typedef __attribute__((ext_vector_type(4))) float floatx4;
typedef __attribute__((ext_vector_type(4))) unsigned short ushort4v;

#define MFMA_BF16(a, b, c) __builtin_amdgcn_mfma_f32_16x16x32_bf16((a), (b), (c), 0, 0, 0)

__device__ __forceinline__ float bf2f(unsigned short u) {
  union { unsigned int i; float f; } v; v.i = ((unsigned int)u) << 16; return v.f;
}
__device__ __forceinline__ unsigned short f2bf(float x) {
  union { float f; unsigned int i; } v; v.f = x;
  unsigned int r = v.i + 0x7FFFu + ((v.i >> 16) & 1u);
  return (unsigned short)(r >> 16);
}
__device__ __forceinline__ short8 ld8(const unsigned short* p) { return *(const short8*)p; }

// Stage NI*256 16B chunks (NI*16 rows... rows = NI*32) of a [rows][64-elem] bf16 tile
// into LDS with XOR swizzle: chunk c of row r stored at slot (c ^ (r&7)).
// Each global_load_lds: 64 lanes x 16B, dest = wave-uniform base + lane*16.
template <int NI>
__device__ __forceinline__ void stageT(unsigned short* lds, const unsigned short* src,
                                       int stride, int tid) {
  #pragma unroll
  for (int inst = 0; inst < NI; ++inst) {
    int qb = inst * 256 + (tid & 192);   // wave-uniform chunk base
    int q = qb + (tid & 63);
    int r = q >> 3;
    int c = (q & 7) ^ (r & 7);
    __builtin_amdgcn_global_load_lds(
        (const __attribute__((address_space(1))) unsigned int*)(src + (size_t)r * stride + (c << 3)),
        (__attribute__((address_space(3))) unsigned int*)(lds + (size_t)qb * 8),
        16, 0, 0);
  }
}

// Read MFMA fragment from a swizzled [rows][64] tile: lane holds row r, k-chunk cj.
__device__ __forceinline__ short8 frag64(const unsigned short* lds, int r, int cj) {
  return *(const short8*)(lds + r * 64 + ((cj ^ (r & 7)) << 3));
}

// ============ weight pre-cast (once per call) ============

// filt/gate [30][512][512][2] fp32 -> WA [30][2(tap)][1024][512] bf16 (rows: 0-511 F, 512-1023 G)
__global__ __launch_bounds__(256) void cast_conv_kernel(
    const float* __restrict__ fw, const float* __restrict__ gw,
    unsigned short* __restrict__ WA)
{
  size_t idx = (size_t)blockIdx.x * 256 + threadIdx.x;    // (l,o,i4) : 30*512*128
  size_t l = idx >> 16;
  int o = (int)((idx >> 7) & 511);
  int i4 = (int)(idx & 127) * 4;
  const float4* fp = (const float4*)(fw + (((l * 512 + o) * 512 + i4) * 2));
  const float4* gp = (const float4*)(gw + (((l * 512 + o) * 512 + i4) * 2));
  float4 f0 = fp[0], f1 = fp[1];
  float4 g0 = gp[0], g1 = gp[1];
  size_t base0 = ((l * 2 + 0) * 1024);
  size_t base1 = ((l * 2 + 1) * 1024);
  *(ushort4v*)&WA[(base0 + o) * 512 + i4]       = (ushort4v){f2bf(f0.x), f2bf(f0.z), f2bf(f1.x), f2bf(f1.z)};
  *(ushort4v*)&WA[(base1 + o) * 512 + i4]       = (ushort4v){f2bf(f0.y), f2bf(f0.w), f2bf(f1.y), f2bf(f1.w)};
  *(ushort4v*)&WA[(base0 + 512 + o) * 512 + i4] = (ushort4v){f2bf(g0.x), f2bf(g0.z), f2bf(g1.x), f2bf(g1.z)};
  *(ushort4v*)&WA[(base1 + 512 + o) * 512 + i4] = (ushort4v){f2bf(g0.y), f2bf(g0.w), f2bf(g1.y), f2bf(g1.w)};
}

// res/skip [30][512][512] fp32 -> RS [30][1024][512] bf16 (rows: 0-511 res, 512-1023 skip)
__global__ __launch_bounds__(256) void cast_rs_kernel(
    const float* __restrict__ rw, const float* __restrict__ sw,
    unsigned short* __restrict__ RS)
{
  size_t idx = (size_t)blockIdx.x * 256 + threadIdx.x;    // 30*512*128
  size_t l = idx >> 16;
  int o = (int)((idx >> 7) & 511);
  int i4 = (int)(idx & 127) * 4;
  float4 r4 = *(const float4*)(rw + ((l * 512 + o) * 512 + i4));
  float4 s4 = *(const float4*)(sw + ((l * 512 + o) * 512 + i4));
  *(ushort4v*)&RS[(l * 1024 + o) * 512 + i4]       = (ushort4v){f2bf(r4.x), f2bf(r4.y), f2bf(r4.z), f2bf(r4.w)};
  *(ushort4v*)&RS[(l * 1024 + 512 + o) * 512 + i4] = (ushort4v){f2bf(s4.x), f2bf(s4.y), f2bf(s4.z), f2bf(s4.w)};
}

// cf/cg [30][512][128] fp32 -> CA [30][1024][128] bf16
__global__ __launch_bounds__(256) void cast_cond_kernel(
    const float* __restrict__ cf, const float* __restrict__ cg,
    unsigned short* __restrict__ CA)
{
  size_t idx = (size_t)blockIdx.x * 256 + threadIdx.x;    // 30*512*32
  size_t l = idx >> 14;
  int o = (int)((idx >> 5) & 511);
  int i4 = (int)(idx & 31) * 4;
  float4 f4 = *(const float4*)(cf + ((l * 512 + o) * 128 + i4));
  float4 g4 = *(const float4*)(cg + ((l * 512 + o) * 128 + i4));
  *(ushort4v*)&CA[(l * 1024 + o) * 128 + i4]       = (ushort4v){f2bf(f4.x), f2bf(f4.y), f2bf(f4.z), f2bf(f4.w)};
  *(ushort4v*)&CA[(l * 1024 + 512 + o) * 128 + i4] = (ushort4v){f2bf(g4.x), f2bf(g4.y), f2bf(g4.z), f2bf(g4.w)};
}

__global__ __launch_bounds__(256) void cast_f1_kernel(
    const float* __restrict__ w, unsigned short* __restrict__ out)
{
  size_t idx = (size_t)blockIdx.x * 256 + threadIdx.x;    // 512*128
  float4 v = *(const float4*)(w + idx * 4);
  *(ushort4v*)&out[idx * 4] = (ushort4v){f2bf(v.x), f2bf(v.y), f2bf(v.z), f2bf(v.w)};
}

// fgb[30][1024]: rows 0-511 = filt_b+cf_b ; 512-1023 = gate_b+cg_b
__global__ __launch_bounds__(256) void cast_bias_kernel(
    const float* __restrict__ fb, const float* __restrict__ cfb,
    const float* __restrict__ gb, const float* __restrict__ cgb,
    float* __restrict__ fgb)
{
  int idx = blockIdx.x * 256 + threadIdx.x;   // 30*1024
  int l = idx >> 10, r = idx & 1023;
  float v;
  if (r < 512) v = fb[l * 512 + r] + cfb[l * 512 + r];
  else         v = gb[l * 512 + r - 512] + cgb[l * 512 + r - 512];
  fgb[idx] = v;
}

// ============ upsample ============

__global__ __launch_bounds__(256) void upsample1_kernel(
    const float* __restrict__ c, const float* __restrict__ up_w,
    const float* __restrict__ up_b, float* __restrict__ u1)
{
  int x = threadIdx.x;
  int h = blockIdx.x;
  const float* w = up_w;
  float acc = 0.f;
  int k1 = (23 - x) & 15;
  #pragma unroll
  for (int dk = 0; dk < 2; ++dk) {
    int kx = k1 + 16 * dk;
    int num = x + kx - 23;
    if (num >= 0) {
      int qq = num >> 4;
      if (qq < 16) {
        #pragma unroll
        for (int ky = 0; ky < 3; ++ky) {
          int hh = h + ky - 1;
          if (hh >= 0 && hh < 128)
            acc += c[hh * 16 + qq] * w[(2 - ky) * 32 + (31 - kx)];
        }
      }
    }
  }
  acc += up_b[0];
  u1[h * 256 + x] = acc > 0.f ? acc : 0.4f * acc;
}

__global__ __launch_bounds__(256) void upsample2_kernel(
    const float* __restrict__ u1, const float* __restrict__ up_w,
    const float* __restrict__ up_b, unsigned short* __restrict__ cu)
{
  int x = blockIdx.x * 256 + threadIdx.x;
  int h = blockIdx.y;
  const float* w = up_w + 96;
  float acc = 0.f;
  int k1 = (23 - x) & 15;
  #pragma unroll
  for (int dk = 0; dk < 2; ++dk) {
    int kx = k1 + 16 * dk;
    int num = x + kx - 23;
    if (num >= 0) {
      int qq = num >> 4;
      if (qq < 256) {
        #pragma unroll
        for (int ky = 0; ky < 3; ++ky) {
          int hh = h + ky - 1;
          if (hh >= 0 && hh < 128)
            acc += u1[hh * 256 + qq] * w[(2 - ky) * 32 + (31 - kx)];
        }
      }
    }
  }
  acc += up_b[1];
  acc = acc > 0.f ? acc : 0.4f * acc;
  cu[(size_t)x * 128 + h] = f2bf(acc);
}

// ============ front conv -> h[t][512] ============
__global__ __launch_bounds__(256) void front_kernel(
    const float* __restrict__ x, const float* __restrict__ fw, const float* __restrict__ fb,
    float* __restrict__ hf, unsigned short* __restrict__ hbf)
{
  __shared__ float xs[40];
  int tid = threadIdx.x;
  int o = blockIdx.y * 256 + tid;
  int t0 = blockIdx.x * 8;
  if (tid < 39) {
    int gx = t0 - 31 + tid;
    xs[tid] = (gx >= 0) ? x[gx] : 0.f;
  }
  __syncthreads();
  float w[32];
  #pragma unroll
  for (int k = 0; k < 32; ++k) w[k] = fw[o * 32 + k];
  float b = fb[o];
  #pragma unroll
  for (int j = 0; j < 8; ++j) {
    float acc = b;
    #pragma unroll
    for (int k = 0; k < 32; ++k) acc += w[k] * xs[j + k];
    acc = acc > 0.f ? acc : 0.f;
    int t = t0 + j;
    hf[(size_t)t * 512 + o] = acc;
    hbf[(size_t)(HPADT + t) * 512 + o] = f2bf(acc);
  }
}

// ============ gemm_a: dual F/G, tile 64oc x 128t, BK=64, dbuf LDS ============
__global__ __launch_bounds__(256) void gemm_a_kernel(
    const unsigned short* __restrict__ WA,   // [2][1024][512]
    const unsigned short* __restrict__ CA,   // [1024][128]
    const float* __restrict__ fgb,           // [1024]
    const unsigned short* __restrict__ hbf,  // [(HPADT+T)][512]
    const unsigned short* __restrict__ cu,   // [T][128]
    unsigned short* __restrict__ obf,        // [T][512]
    const int d)
{
  __shared__ unsigned short Af[2][64 * 64];
  __shared__ unsigned short Ag[2][64 * 64];
  __shared__ unsigned short Xs[2][128 * 64];

  const int tid = threadIdx.x;
  const int lane = tid & 63;
  const int wave = tid >> 6;
  const int lm = lane & 15, qd = lane >> 4;
  const int n0 = blockIdx.x * 128;
  const int m0 = blockIdx.y * 64;
  const int wm = (wave & 1) * 32;
  const int wn = (wave >> 1) * 64;

  floatx4 accF[2][4], accG[2][4];
  #pragma unroll
  for (int a = 0; a < 2; ++a)
    #pragma unroll
    for (int b = 0; b < 4; ++b) {
      accF[a][b] = (floatx4){0.f, 0.f, 0.f, 0.f};
      accG[a][b] = (floatx4){0.f, 0.f, 0.f, 0.f};
    }

  auto stage_step = [&](int s, int b) {
    const unsigned short *ab, *xb;
    int astr, xstr, k0;
    if (s < 16) {
      int tap = s >> 3;
      k0 = (s & 7) * 64;
      ab = WA + (size_t)tap * 524288;
      astr = 512;
      xb = hbf + ((size_t)(HPADT + n0 - (tap ? 0 : d))) * 512;
      xstr = 512;
    } else {
      k0 = (s & 1) * 64;
      ab = CA; astr = 128;
      xb = cu + (size_t)n0 * 128; xstr = 128;
    }
    stageT<2>(&Af[b][0], ab + (size_t)m0 * astr + k0, astr, tid);
    stageT<2>(&Ag[b][0], ab + (size_t)(512 + m0) * astr + k0, astr, tid);
    stageT<4>(&Xs[b][0], xb + k0, xstr, tid);
  };

  stage_step(0, 0);
  for (int s = 0; s < 18; ++s) {
    __syncthreads();                       // fill(s) complete; prev step's ds_reads done
    if (s < 17) stage_step(s + 1, (s + 1) & 1);
    const unsigned short* af = &Af[s & 1][0];
    const unsigned short* ag = &Ag[s & 1][0];
    const unsigned short* xs = &Xs[s & 1][0];
    #pragma unroll
    for (int j = 0; j < 2; ++j) {
      int cj = qd + 4 * j;
      short8 a[2], g[2], xv[4];
      a[0] = frag64(af, wm + lm, cj);
      a[1] = frag64(af, wm + 16 + lm, cj);
      g[0] = frag64(ag, wm + lm, cj);
      g[1] = frag64(ag, wm + 16 + lm, cj);
      #pragma unroll
      for (int nt = 0; nt < 4; ++nt) xv[nt] = frag64(xs, wn + nt * 16 + lm, cj);
      #pragma unroll
      for (int mt = 0; mt < 2; ++mt)
        #pragma unroll
        for (int nt = 0; nt < 4; ++nt) {
          accF[mt][nt] = MFMA_BF16(a[mt], xv[nt], accF[mt][nt]);
          accG[mt][nt] = MFMA_BF16(g[mt], xv[nt], accG[mt][nt]);
        }
    }
  }

  #pragma unroll
  for (int mt = 0; mt < 2; ++mt) {
    int oc0 = m0 + wm + mt * 16 + qd * 4;
    floatx4 fb4 = *(const floatx4*)&fgb[oc0];
    floatx4 gb4 = *(const floatx4*)&fgb[512 + oc0];
    #pragma unroll
    for (int nt = 0; nt < 4; ++nt) {
      int t = n0 + wn + nt * 16 + lm;
      ushort4v o4;
      #pragma unroll
      for (int r = 0; r < 4; ++r) {
        float f = accF[mt][nt][r] + fb4[r];
        float g = accG[mt][nt][r] + gb4[r];
        float ef = __expf(-2.f * f);
        float th = (1.f - ef) / (1.f + ef);
        float sg = 1.f / (1.f + __expf(-g));
        o4[r] = f2bf(th * sg);
      }
      *(ushort4v*)&obf[(size_t)t * 512 + oc0] = o4;
    }
  }
}

// ============ gemm_b: dual R/S, tile 64oc x 128t, BK=64, dbuf LDS ============
__global__ __launch_bounds__(256) void gemm_b_kernel(
    const unsigned short* __restrict__ RS,   // [1024][512]
    const float* __restrict__ rb, const float* __restrict__ sb,
    const unsigned short* __restrict__ obf,  // [T][512]
    float* __restrict__ hf, unsigned short* __restrict__ hbf,
    float* __restrict__ skip, unsigned short* __restrict__ skipbf,
    const int first, const int last)
{
  __shared__ unsigned short Ar[2][64 * 64];
  __shared__ unsigned short As_[2][64 * 64];
  __shared__ unsigned short Xs[2][128 * 64];

  const int tid = threadIdx.x;
  const int lane = tid & 63;
  const int wave = tid >> 6;
  const int lm = lane & 15, qd = lane >> 4;
  const int n0 = blockIdx.x * 128;
  const int m0 = blockIdx.y * 64;
  const int wm = (wave & 1) * 32;
  const int wn = (wave >> 1) * 64;

  floatx4 accR[2][4], accS[2][4];
  #pragma unroll
  for (int a = 0; a < 2; ++a)
    #pragma unroll
    for (int b = 0; b < 4; ++b) {
      accR[a][b] = (floatx4){0.f, 0.f, 0.f, 0.f};
      accS[a][b] = (floatx4){0.f, 0.f, 0.f, 0.f};
    }

  auto stage_step = [&](int s, int b) {
    int k0 = s * 64;
    stageT<2>(&Ar[b][0], RS + (size_t)m0 * 512 + k0, 512, tid);
    stageT<2>(&As_[b][0], RS + (size_t)(512 + m0) * 512 + k0, 512, tid);
    stageT<4>(&Xs[b][0], obf + (size_t)n0 * 512 + k0, 512, tid);
  };

  stage_step(0, 0);
  for (int s = 0; s < 8; ++s) {
    __syncthreads();
    if (s < 7) stage_step(s + 1, (s + 1) & 1);
    const unsigned short* ar = &Ar[s & 1][0];
    const unsigned short* as = &As_[s & 1][0];
    const unsigned short* xs = &Xs[s & 1][0];
    #pragma unroll
    for (int j = 0; j < 2; ++j) {
      int cj = qd + 4 * j;
      short8 a[2], g[2], xv[4];
      a[0] = frag64(ar, wm + lm, cj);
      a[1] = frag64(ar, wm + 16 + lm, cj);
      g[0] = frag64(as, wm + lm, cj);
      g[1] = frag64(as, wm + 16 + lm, cj);
      #pragma unroll
      for (int nt = 0; nt < 4; ++nt) xv[nt] = frag64(xs, wn + nt * 16 + lm, cj);
      #pragma unroll
      for (int mt = 0; mt < 2; ++mt)
        #pragma unroll
        for (int nt = 0; nt < 4; ++nt) {
          accR[mt][nt] = MFMA_BF16(a[mt], xv[nt], accR[mt][nt]);
          accS[mt][nt] = MFMA_BF16(g[mt], xv[nt], accS[mt][nt]);
        }
    }
  }

  #pragma unroll
  for (int mt = 0; mt < 2; ++mt) {
    int oc0 = m0 + wm + mt * 16 + qd * 4;
    floatx4 rb4 = *(const floatx4*)&rb[oc0];
    floatx4 sb4 = *(const floatx4*)&sb[oc0];
    #pragma unroll
    for (int nt = 0; nt < 4; ++nt) {
      int t = n0 + wn + nt * 16 + lm;
      size_t base = (size_t)t * 512 + oc0;
      floatx4 h4 = *(const floatx4*)&hf[base];
      floatx4 s4;
      if (first) s4 = (floatx4){0.f, 0.f, 0.f, 0.f};
      else s4 = *(const floatx4*)&skip[base];
      ushort4v hb4;
      #pragma unroll
      for (int r = 0; r < 4; ++r) {
        float hv = (h4[r] + accR[mt][nt][r] + rb4[r]) * SQRT_HALF;
        h4[r] = hv;
        hb4[r] = f2bf(hv);
        s4[r] = s4[r] + accS[mt][nt][r] + sb4[r];
      }
      *(floatx4*)&hf[base] = h4;
      *(ushort4v*)&hbf[(size_t)(HPADT + t) * 512 + oc0] = hb4;
      *(floatx4*)&skip[base] = s4;
      if (last) {
        ushort4v sk4;
        #pragma unroll
        for (int r = 0; r < 4; ++r) sk4[r] = f2bf(s4[r] > 0.f ? s4[r] : 0.f);
        *(ushort4v*)&skipbf[base] = sk4;
      }
    }
  }
}

// ============ final1: single-output, tile 64 x 128, BK=64, dbuf LDS ============
__global__ __launch_bounds__(256) void final1_kernel(
    const unsigned short* __restrict__ W1,       // [512][512]
    const float* __restrict__ b1,
    const unsigned short* __restrict__ skipbf,   // [T][512]
    unsigned short* __restrict__ t1)
{
  __shared__ unsigned short Aw[2][64 * 64];
  __shared__ unsigned short Xs[2][128 * 64];

  const int tid = threadIdx.x;
  const int lane = tid & 63;
  const int wave = tid >> 6;
  const int lm = lane & 15, qd = lane >> 4;
  const int n0 = blockIdx.x * 128;
  const int m0 = blockIdx.y * 64;
  const int wm = (wave & 1) * 32;
  const int wn = (wave >> 1) * 64;

  floatx4 acc[2][4];
  #pragma unroll
  for (int a = 0; a < 2; ++a)
    #pragma unroll
    for (int b = 0; b < 4; ++b) acc[a][b] = (floatx4){0.f, 0.f, 0.f, 0.f};

  auto stage_step = [&](int s, int b) {
    int k0 = s * 64;
    stageT<2>(&Aw[b][0], W1 + (size_t)m0 * 512 + k0, 512, tid);
    stageT<4>(&Xs[b][0], skipbf + (size_t)n0 * 512 + k0, 512, tid);
  };

  stage_step(0, 0);
  for (int s = 0; s < 8; ++s) {
    __syncthreads();
    if (s < 7) stage_step(s + 1, (s + 1) & 1);
    const unsigned short* aw = &Aw[s & 1][0];
    const unsigned short* xs = &Xs[s & 1][0];
    #pragma unroll
    for (int j = 0; j < 2; ++j) {
      int cj = qd + 4 * j;
      short8 a[2], xv[4];
      a[0] = frag64(aw, wm + lm, cj);
      a[1] = frag64(aw, wm + 16 + lm, cj);
      #pragma unroll
      for (int nt = 0; nt < 4; ++nt) xv[nt] = frag64(xs, wn + nt * 16 + lm, cj);
      #pragma unroll
      for (int mt = 0; mt < 2; ++mt)
        #pragma unroll
        for (int nt = 0; nt < 4; ++nt)
          acc[mt][nt] = MFMA_BF16(a[mt], xv[nt], acc[mt][nt]);
    }
  }

  #pragma unroll
  for (int mt = 0; mt < 2; ++mt) {
    int oc0 = m0 + wm + mt * 16 + qd * 4;
    floatx4 b4 = *(const floatx4*)&b1[oc0];
    #pragma unroll
    for (int nt = 0; nt < 4; ++nt) {
      int t = n0 + wn + nt * 16 + lm;
      ushort4v o4;
      #pragma unroll
      for (int r = 0; r < 4; ++r) {
        float v = acc[mt][nt][r] + b4[r];
        o4[r] = f2bf(v > 0.f ? v : 0.f);
      }
      *(ushort4v*)&t1[(size_t)t * 512 + oc0] = o4;
    }
  }
}

// ============ final2 ============
__global__ __launch_bounds__(256) void final2_kernel(
    const float* __restrict__ W2, const float* __restrict__ b2,
    const unsigned short* __restrict__ t1, float* __restrict__ out)
{
  int t = blockIdx.x * 256 + threadIdx.x;
  const unsigned short* row = t1 + (size_t)t * 512;
  float a0 = 0.f, a1 = 0.f;
  for (int i = 0; i < 512; i += 8) {
    short8 v = ld8(row + i);
    #pragma unroll
    for (int r = 0; r < 8; ++r) {
      float f = bf2f((unsigned short)v[r]);
      a0 += W2[i + r] * f;
      a1 += W2[512 + i + r] * f;
    }
  }
  out[t] = a0 + b2[0];
  out[TLEN + t] = a1 + b2[1];
}

extern "C" void kernel_launch(void* const* d_in, const int* in_sizes, int n_in,
                              void* d_out, int out_size, void* d_ws, size_t ws_size,
                              hipStream_t stream) {
  (void)in_sizes; (void)n_in; (void)out_size; (void)ws_size;
  const float* x       = (const float*)d_in[0];
  const float* c       = (const float*)d_in[1];
  const float* front_w = (const float*)d_in[2];
  const float* front_b = (const float*)d_in[3];
  const float* filt_w  = (const float*)d_in[4];
  const float* filt_b  = (const float*)d_in[5];
  const float* gate_w  = (const float*)d_in[6];
  const float* gate_b  = (const float*)d_in[7];
  const float* cf_w    = (const float*)d_in[8];
  const float* cf_b    = (const float*)d_in[9];
  const float* cg_w    = (const float*)d_in[10];
  const float* cg_b    = (const float*)d_in[11];
  const float* res_w   = (const float*)d_in[12];
  const float* res_b   = (const float*)d_in[13];
  const float* skip_w  = (const float*)d_in[14];
  const float* skip_b  = (const float*)d_in[15];
  const float* fin1_w  = (const float*)d_in[16];
  const float* fin1_b  = (const float*)d_in[17];
  const float* fin2_w  = (const float*)d_in[18];
  const float* fin2_b  = (const float*)d_in[19];
  const float* up_w    = (const float*)d_in[20];
  const float* up_b    = (const float*)d_in[21];

  char* ws = (char*)d_ws;
  auto alloc = [&](size_t bytes) {
    char* p = ws;
    ws += (bytes + 255) & ~(size_t)255;
    return p;
  };
  unsigned short* WA     = (unsigned short*)alloc((size_t)30 * 2 * 1024 * 512 * 2);
  unsigned short* RS     = (unsigned short*)alloc((size_t)30 * 1024 * 512 * 2);
  unsigned short* CA     = (unsigned short*)alloc((size_t)30 * 1024 * 128 * 2);
  unsigned short* F1c    = (unsigned short*)alloc((size_t)512 * 512 * 2);
  float* fgb             = (float*)alloc((size_t)30 * 1024 * 4);
  float* u1              = (float*)alloc((size_t)128 * 256 * 4);
  unsigned short* cu     = (unsigned short*)alloc((size_t)TLEN * 128 * 2);
  float* hf              = (float*)alloc((size_t)TLEN * 512 * 4);
  unsigned short* hbf    = (unsigned short*)alloc((size_t)(HPADT + TLEN) * 512 * 2);
  unsigned short* obf    = (unsigned short*)alloc((size_t)TLEN * 512 * 2);
  float* skip            = (float*)alloc((size_t)TLEN * 512 * 4);
  unsigned short* skipbf = (unsigned short*)alloc((size_t)TLEN * 512 * 2);
  unsigned short* t1     = (unsigned short*)alloc((size_t)TLEN * 512 * 2);
  float* out             = (float*)d_out;

  // zero the left pad of hbf (tap t-d reads 0 for t < d)
  hipMemsetAsync(hbf, 0, (size_t)HPADT * 512 * 2, stream);

  cast_conv_kernel<<<7680, 256, 0, stream>>>(filt_w, gate_w, WA);
  cast_rs_kernel<<<7680, 256, 0, stream>>>(res_w, skip_w, RS);
  cast_cond_kernel<<<1920, 256, 0, stream>>>(cf_w, cg_w, CA);
  cast_f1_kernel<<<256, 256, 0, stream>>>(fin1_w, F1c);
  cast_bias_kernel<<<120, 256, 0, stream>>>(filt_b, cf_b, gate_b, cg_b, fgb);

  upsample1_kernel<<<dim3(128), 256, 0, stream>>>(c, up_w, up_b, u1);
  upsample2_kernel<<<dim3(16, 128), 256, 0, stream>>>(u1, up_w, up_b, cu);
  front_kernel<<<dim3(512, 2), 256, 0, stream>>>(x, front_w, front_b, hf, hbf);

  for (int l = 0; l < 30; ++l) {
    int d = 1 << (l % 10);
    gemm_a_kernel<<<dim3(32, 8), 256, 0, stream>>>(
        WA + (size_t)l * 2 * 524288, CA + (size_t)l * 131072,
        fgb + (size_t)l * 1024,
        hbf, cu, obf, d);
    gemm_b_kernel<<<dim3(32, 8), 256, 0, stream>>>(
        RS + (size_t)l * 524288,
        res_b + (size_t)l * 512, skip_b + (size_t)l * 512,
        obf, hf, hbf, skip, skipbf, (l == 0) ? 1 : 0, (l == 29) ? 1 : 0);
  }

  final1_kernel<<<dim3(32, 8), 256, 0, stream>>>(F1c, fin1_b, skipbf, t1);
  final2_kernel<<<16, 256, 0, stream>>>(fin2_w, fin2_b, t1, out);
}

// Round 4
// 1287.253 us; speedup vs baseline: 1.8016x; 1.1683x over previous
//
#include <hip/hip_runtime.h>
#include <hip/hip_bf16.h>

#define TLEN 4096
#define HPADT 512
#define SQRT_HALF 0.70710678118654752f

typedef __attribute__((ext_vector_type(8))) short short8;
typedef __attribute__((ext_vector_type(4))) float floatx4;
typedef __attribute__((ext_vector_type(4))) unsigned short ushort4v;

#define MFMA_BF16(a, b, c) __builtin_amdgcn_mfma_f32_16x16x32_bf16((a), (b), (c), 0, 0, 0)

__device__ __forceinline__ float bf2f(unsigned short u) {
  union { unsigned int i; float f; } v; v.i = ((unsigned int)u) << 16; return v.f;
}
__device__ __forceinline__ unsigned short f2bf(float x) {
  union { float f; unsigned int i; } v; v.f = x;
  unsigned int r = v.i + 0x7FFFu + ((v.i >> 16) & 1u);
  return (unsigned short)(r >> 16);
}
__device__ __forceinline__ short8 ld8(const unsigned short* p) { return *(const short8*)p; }

// Stage NI*256 16B chunks of a [rows][128-elem] bf16 tile into LDS with XOR
// swizzle: data chunk c of row r lands at slot (c ^ (r&15)).
// dest = wave-uniform base + lane*16 (global_load_lds constraint).
template <int NI>
__device__ __forceinline__ void stage128(unsigned short* lds, const unsigned short* src,
                                         int stride, int tid) {
  #pragma unroll
  for (int inst = 0; inst < NI; ++inst) {
    int qb = inst * 256 + (tid & 192);   // wave-uniform chunk base
    int q = qb + (tid & 63);
    int r = q >> 4;
    int c = (q & 15) ^ (r & 15);
    __builtin_amdgcn_global_load_lds(
        (const __attribute__((address_space(1))) unsigned int*)(src + (size_t)r * stride + (c << 3)),
        (__attribute__((address_space(3))) unsigned int*)(lds + qb * 8),
        16, 0, 0);
  }
}

// Read MFMA fragment from swizzled [rows][128] tile (row r, k-chunk cj in 0..15).
__device__ __forceinline__ short8 frag128(const unsigned short* lds, int r, int cj) {
  return *(const short8*)(lds + r * 128 + ((cj ^ (r & 15)) << 3));
}

// ============ merged weight pre-cast (once per call) ============
// seg0 [0,7680):      filt/gate [30][512][512][2] -> WA [30][2][1024][512]
// seg1 [7680,15360):  res/skip  [30][512][512]    -> RS [30][1024][512]
// seg2 [15360,17280): cf/cg     [30][512][128]    -> CA [30][1024][128]
// seg3 [17280,17536): fin1_w    [512][512]        -> F1c
// seg4 [17536,17656): biases -> fgb [30][1024]
__global__ __launch_bounds__(256) void cast_all_kernel(
    const float* __restrict__ fw, const float* __restrict__ gw,
    const float* __restrict__ rw, const float* __restrict__ sw,
    const float* __restrict__ cf, const float* __restrict__ cg,
    const float* __restrict__ f1, const float* __restrict__ fb,
    const float* __restrict__ cfb, const float* __restrict__ gb,
    const float* __restrict__ cgb,
    unsigned short* __restrict__ WA, unsigned short* __restrict__ RS,
    unsigned short* __restrict__ CA, unsigned short* __restrict__ F1c,
    float* __restrict__ fgb)
{
  int b = blockIdx.x;
  if (b < 7680) {
    size_t idx = (size_t)b * 256 + threadIdx.x;      // 30*512*128
    size_t l = idx >> 16;
    int o = (int)((idx >> 7) & 511);
    int i4 = (int)(idx & 127) * 4;
    const float4* fp = (const float4*)(fw + (((l * 512 + o) * 512 + i4) * 2));
    const float4* gp = (const float4*)(gw + (((l * 512 + o) * 512 + i4) * 2));
    float4 f0 = fp[0], f1v = fp[1];
    float4 g0 = gp[0], g1 = gp[1];
    size_t base0 = ((l * 2 + 0) * 1024);
    size_t base1 = ((l * 2 + 1) * 1024);
    *(ushort4v*)&WA[(base0 + o) * 512 + i4]       = (ushort4v){f2bf(f0.x), f2bf(f0.z), f2bf(f1v.x), f2bf(f1v.z)};
    *(ushort4v*)&WA[(base1 + o) * 512 + i4]       = (ushort4v){f2bf(f0.y), f2bf(f0.w), f2bf(f1v.y), f2bf(f1v.w)};
    *(ushort4v*)&WA[(base0 + 512 + o) * 512 + i4] = (ushort4v){f2bf(g0.x), f2bf(g0.z), f2bf(g1.x), f2bf(g1.z)};
    *(ushort4v*)&WA[(base1 + 512 + o) * 512 + i4] = (ushort4v){f2bf(g0.y), f2bf(g0.w), f2bf(g1.y), f2bf(g1.w)};
  } else if (b < 15360) {
    size_t idx = (size_t)(b - 7680) * 256 + threadIdx.x;   // 30*512*128
    size_t l = idx >> 16;
    int o = (int)((idx >> 7) & 511);
    int i4 = (int)(idx & 127) * 4;
    float4 r4 = *(const float4*)(rw + ((l * 512 + o) * 512 + i4));
    float4 s4 = *(const float4*)(sw + ((l * 512 + o) * 512 + i4));
    *(ushort4v*)&RS[(l * 1024 + o) * 512 + i4]       = (ushort4v){f2bf(r4.x), f2bf(r4.y), f2bf(r4.z), f2bf(r4.w)};
    *(ushort4v*)&RS[(l * 1024 + 512 + o) * 512 + i4] = (ushort4v){f2bf(s4.x), f2bf(s4.y), f2bf(s4.z), f2bf(s4.w)};
  } else if (b < 17280) {
    size_t idx = (size_t)(b - 15360) * 256 + threadIdx.x;  // 30*512*32
    size_t l = idx >> 14;
    int o = (int)((idx >> 5) & 511);
    int i4 = (int)(idx & 31) * 4;
    float4 f4 = *(const float4*)(cf + ((l * 512 + o) * 128 + i4));
    float4 g4 = *(const float4*)(cg + ((l * 512 + o) * 128 + i4));
    *(ushort4v*)&CA[(l * 1024 + o) * 128 + i4]       = (ushort4v){f2bf(f4.x), f2bf(f4.y), f2bf(f4.z), f2bf(f4.w)};
    *(ushort4v*)&CA[(l * 1024 + 512 + o) * 128 + i4] = (ushort4v){f2bf(g4.x), f2bf(g4.y), f2bf(g4.z), f2bf(g4.w)};
  } else if (b < 17536) {
    size_t idx = (size_t)(b - 17280) * 256 + threadIdx.x;  // 512*128
    float4 v = *(const float4*)(f1 + idx * 4);
    *(ushort4v*)&F1c[idx * 4] = (ushort4v){f2bf(v.x), f2bf(v.y), f2bf(v.z), f2bf(v.w)};
  } else {
    int idx = (b - 17536) * 256 + threadIdx.x;             // 30*1024
    int l = idx >> 10, r = idx & 1023;
    float v;
    if (r < 512) v = fb[l * 512 + r] + cfb[l * 512 + r];
    else         v = gb[l * 512 + r - 512] + cgb[l * 512 + r - 512];
    fgb[idx] = v;
  }
}

// ============ upsample ============

__global__ __launch_bounds__(256) void upsample1_kernel(
    const float* __restrict__ c, const float* __restrict__ up_w,
    const float* __restrict__ up_b, float* __restrict__ u1)
{
  int x = threadIdx.x;
  int h = blockIdx.x;
  const float* w = up_w;
  float acc = 0.f;
  int k1 = (23 - x) & 15;
  #pragma unroll
  for (int dk = 0; dk < 2; ++dk) {
    int kx = k1 + 16 * dk;
    int num = x + kx - 23;
    if (num >= 0) {
      int qq = num >> 4;
      if (qq < 16) {
        #pragma unroll
        for (int ky = 0; ky < 3; ++ky) {
          int hh = h + ky - 1;
          if (hh >= 0 && hh < 128)
            acc += c[hh * 16 + qq] * w[(2 - ky) * 32 + (31 - kx)];
        }
      }
    }
  }
  acc += up_b[0];
  u1[h * 256 + x] = acc > 0.f ? acc : 0.4f * acc;
}

__global__ __launch_bounds__(256) void upsample2_kernel(
    const float* __restrict__ u1, const float* __restrict__ up_w,
    const float* __restrict__ up_b, unsigned short* __restrict__ cu)
{
  int x = blockIdx.x * 256 + threadIdx.x;
  int h = blockIdx.y;
  const float* w = up_w + 96;
  float acc = 0.f;
  int k1 = (23 - x) & 15;
  #pragma unroll
  for (int dk = 0; dk < 2; ++dk) {
    int kx = k1 + 16 * dk;
    int num = x + kx - 23;
    if (num >= 0) {
      int qq = num >> 4;
      if (qq < 256) {
        #pragma unroll
        for (int ky = 0; ky < 3; ++ky) {
          int hh = h + ky - 1;
          if (hh >= 0 && hh < 128)
            acc += u1[hh * 256 + qq] * w[(2 - ky) * 32 + (31 - kx)];
        }
      }
    }
  }
  acc += up_b[1];
  acc = acc > 0.f ? acc : 0.4f * acc;
  cu[(size_t)x * 128 + h] = f2bf(acc);
}

// ============ front conv -> h[t][512] ============
__global__ __launch_bounds__(256) void front_kernel(
    const float* __restrict__ x, const float* __restrict__ fw, const float* __restrict__ fb,
    float* __restrict__ hf, unsigned short* __restrict__ hbf)
{
  __shared__ float xs[40];
  int tid = threadIdx.x;
  int o = blockIdx.y * 256 + tid;
  int t0 = blockIdx.x * 8;
  if (tid < 39) {
    int gx = t0 - 31 + tid;
    xs[tid] = (gx >= 0) ? x[gx] : 0.f;
  }
  __syncthreads();
  float w[32];
  #pragma unroll
  for (int k = 0; k < 32; ++k) w[k] = fw[o * 32 + k];
  float b = fb[o];
  #pragma unroll
  for (int j = 0; j < 8; ++j) {
    float acc = b;
    #pragma unroll
    for (int k = 0; k < 32; ++k) acc += w[k] * xs[j + k];
    acc = acc > 0.f ? acc : 0.f;
    int t = t0 + j;
    hf[(size_t)t * 512 + o] = acc;
    hbf[(size_t)(HPADT + t) * 512 + o] = f2bf(acc);
  }
}

// ============ gemm_a: dual F/G, tile 64oc x 128t, BK=128, dbuf LDS (128 KB) ============
__global__ __launch_bounds__(256) void gemm_a_kernel(
    const unsigned short* __restrict__ WA,   // [2][1024][512]
    const unsigned short* __restrict__ CA,   // [1024][128]
    const float* __restrict__ fgb,           // [1024]
    const unsigned short* __restrict__ hbf,  // [(HPADT+T)][512]
    const unsigned short* __restrict__ cu,   // [T][128]
    unsigned short* __restrict__ obf,        // [T][512]
    const int d)
{
  __shared__ unsigned short Af[2][64 * 128];
  __shared__ unsigned short Ag[2][64 * 128];
  __shared__ unsigned short Xs[2][128 * 128];

  const int tid = threadIdx.x;
  const int lane = tid & 63;
  const int wave = tid >> 6;
  const int lm = lane & 15, qd = lane >> 4;
  const int n0 = blockIdx.x * 128;
  const int m0 = blockIdx.y * 64;
  const int wm = (wave & 1) * 32;
  const int wn = (wave >> 1) * 64;

  floatx4 accF[2][4], accG[2][4];
  #pragma unroll
  for (int a = 0; a < 2; ++a)
    #pragma unroll
    for (int b = 0; b < 4; ++b) {
      accF[a][b] = (floatx4){0.f, 0.f, 0.f, 0.f};
      accG[a][b] = (floatx4){0.f, 0.f, 0.f, 0.f};
    }

  auto stage_step = [&](int s, int b) {
    if (s < 8) {
      int tap = s >> 2;
      int k0 = (s & 3) * 128;
      const unsigned short* ab = WA + (size_t)tap * 524288;
      stage128<4>(&Af[b][0], ab + (size_t)m0 * 512 + k0, 512, tid);
      stage128<4>(&Ag[b][0], ab + (size_t)(512 + m0) * 512 + k0, 512, tid);
      stage128<8>(&Xs[b][0], hbf + (size_t)(HPADT + n0 - (tap ? 0 : d)) * 512 + k0, 512, tid);
    } else {
      stage128<4>(&Af[b][0], CA + (size_t)m0 * 128, 128, tid);
      stage128<4>(&Ag[b][0], CA + (size_t)(512 + m0) * 128, 128, tid);
      stage128<8>(&Xs[b][0], cu + (size_t)n0 * 128, 128, tid);
    }
  };

  stage_step(0, 0);
  for (int s = 0; s < 9; ++s) {
    __syncthreads();
    if (s < 8) stage_step(s + 1, (s + 1) & 1);
    const unsigned short* af = &Af[s & 1][0];
    const unsigned short* ag = &Ag[s & 1][0];
    const unsigned short* xs = &Xs[s & 1][0];
    #pragma unroll
    for (int j = 0; j < 4; ++j) {
      int cj = j * 4 + qd;
      short8 a[2], g[2], xv[4];
      a[0] = frag128(af, wm + lm, cj);
      a[1] = frag128(af, wm + 16 + lm, cj);
      g[0] = frag128(ag, wm + lm, cj);
      g[1] = frag128(ag, wm + 16 + lm, cj);
      #pragma unroll
      for (int nt = 0; nt < 4; ++nt) xv[nt] = frag128(xs, wn + nt * 16 + lm, cj);
      #pragma unroll
      for (int mt = 0; mt < 2; ++mt)
        #pragma unroll
        for (int nt = 0; nt < 4; ++nt) {
          accF[mt][nt] = MFMA_BF16(a[mt], xv[nt], accF[mt][nt]);
          accG[mt][nt] = MFMA_BF16(g[mt], xv[nt], accG[mt][nt]);
        }
    }
  }

  #pragma unroll
  for (int mt = 0; mt < 2; ++mt) {
    int oc0 = m0 + wm + mt * 16 + qd * 4;
    floatx4 fb4 = *(const floatx4*)&fgb[oc0];
    floatx4 gb4 = *(const floatx4*)&fgb[512 + oc0];
    #pragma unroll
    for (int nt = 0; nt < 4; ++nt) {
      int t = n0 + wn + nt * 16 + lm;
      ushort4v o4;
      #pragma unroll
      for (int r = 0; r < 4; ++r) {
        float f = accF[mt][nt][r] + fb4[r];
        float g = accG[mt][nt][r] + gb4[r];
        float ef = __expf(-2.f * f);
        float th = (1.f - ef) / (1.f + ef);
        float sg = 1.f / (1.f + __expf(-g));
        o4[r] = f2bf(th * sg);
      }
      *(ushort4v*)&obf[(size_t)t * 512 + oc0] = o4;
    }
  }
}

// ============ gemm_b: dual R/S, tile 64oc x 128t, BK=128, dbuf LDS (128 KB) ============
__global__ __launch_bounds__(256) void gemm_b_kernel(
    const unsigned short* __restrict__ RS,   // [1024][512]
    const float* __restrict__ rb, const float* __restrict__ sb,
    const unsigned short* __restrict__ obf,  // [T][512]
    float* __restrict__ hf, unsigned short* __restrict__ hbf,
    float* __restrict__ skip, unsigned short* __restrict__ skipbf,
    const int first, const int last)
{
  __shared__ unsigned short Ar[2][64 * 128];
  __shared__ unsigned short As_[2][64 * 128];
  __shared__ unsigned short Xs[2][128 * 128];

  const int tid = threadIdx.x;
  const int lane = tid & 63;
  const int wave = tid >> 6;
  const int lm = lane & 15, qd = lane >> 4;
  const int n0 = blockIdx.x * 128;
  const int m0 = blockIdx.y * 64;
  const int wm = (wave & 1) * 32;
  const int wn = (wave >> 1) * 64;

  floatx4 accR[2][4], accS[2][4];
  #pragma unroll
  for (int a = 0; a < 2; ++a)
    #pragma unroll
    for (int b = 0; b < 4; ++b) {
      accR[a][b] = (floatx4){0.f, 0.f, 0.f, 0.f};
      accS[a][b] = (floatx4){0.f, 0.f, 0.f, 0.f};
    }

  auto stage_step = [&](int s, int b) {
    int k0 = s * 128;
    stage128<4>(&Ar[b][0], RS + (size_t)m0 * 512 + k0, 512, tid);
    stage128<4>(&As_[b][0], RS + (size_t)(512 + m0) * 512 + k0, 512, tid);
    stage128<8>(&Xs[b][0], obf + (size_t)n0 * 512 + k0, 512, tid);
  };

  stage_step(0, 0);
  for (int s = 0; s < 4; ++s) {
    __syncthreads();
    if (s < 3) stage_step(s + 1, (s + 1) & 1);
    const unsigned short* ar = &Ar[s & 1][0];
    const unsigned short* as = &As_[s & 1][0];
    const unsigned short* xs = &Xs[s & 1][0];
    #pragma unroll
    for (int j = 0; j < 4; ++j) {
      int cj = j * 4 + qd;
      short8 a[2], g[2], xv[4];
      a[0] = frag128(ar, wm + lm, cj);
      a[1] = frag128(ar, wm + 16 + lm, cj);
      g[0] = frag128(as, wm + lm, cj);
      g[1] = frag128(as, wm + 16 + lm, cj);
      #pragma unroll
      for (int nt = 0; nt < 4; ++nt) xv[nt] = frag128(xs, wn + nt * 16 + lm, cj);
      #pragma unroll
      for (int mt = 0; mt < 2; ++mt)
        #pragma unroll
        for (int nt = 0; nt < 4; ++nt) {
          accR[mt][nt] = MFMA_BF16(a[mt], xv[nt], accR[mt][nt]);
          accS[mt][nt] = MFMA_BF16(g[mt], xv[nt], accS[mt][nt]);
        }
    }
  }

  #pragma unroll
  for (int mt = 0; mt < 2; ++mt) {
    int oc0 = m0 + wm + mt * 16 + qd * 4;
    floatx4 rb4 = *(const floatx4*)&rb[oc0];
    floatx4 sb4 = *(const floatx4*)&sb[oc0];
    #pragma unroll
    for (int nt = 0; nt < 4; ++nt) {
      int t = n0 + wn + nt * 16 + lm;
      size_t base = (size_t)t * 512 + oc0;
      floatx4 h4 = *(const floatx4*)&hf[base];
      floatx4 s4;
      if (first) s4 = (floatx4){0.f, 0.f, 0.f, 0.f};
      else s4 = *(const floatx4*)&skip[base];
      ushort4v hb4;
      #pragma unroll
      for (int r = 0; r < 4; ++r) {
        float hv = (h4[r] + accR[mt][nt][r] + rb4[r]) * SQRT_HALF;
        h4[r] = hv;
        hb4[r] = f2bf(hv);
        s4[r] = s4[r] + accS[mt][nt][r] + sb4[r];
      }
      *(floatx4*)&hf[base] = h4;
      *(ushort4v*)&hbf[(size_t)(HPADT + t) * 512 + oc0] = hb4;
      *(floatx4*)&skip[base] = s4;
      if (last) {
        ushort4v sk4;
        #pragma unroll
        for (int r = 0; r < 4; ++r) sk4[r] = f2bf(s4[r] > 0.f ? s4[r] : 0.f);
        *(ushort4v*)&skipbf[base] = sk4;
      }
    }
  }
}

// ============ final1: tile 64 x 128, BK=128, dbuf LDS (96 KB) ============
__global__ __launch_bounds__(256) void final1_kernel(
    const unsigned short* __restrict__ W1,       // [512][512]
    const float* __restrict__ b1,
    const unsigned short* __restrict__ skipbf,   // [T][512]
    unsigned short* __restrict__ t1)
{
  __shared__ unsigned short Aw[2][64 * 128];
  __shared__ unsigned short Xs[2][128 * 128];

  const int tid = threadIdx.x;
  const int lane = tid & 63;
  const int wave = tid >> 6;
  const int lm = lane & 15, qd = lane >> 4;
  const int n0 = blockIdx.x * 128;
  const int m0 = blockIdx.y * 64;
  const int wm = (wave & 1) * 32;
  const int wn = (wave >> 1) * 64;

  floatx4 acc[2][4];
  #pragma unroll
  for (int a = 0; a < 2; ++a)
    #pragma unroll
    for (int b = 0; b < 4; ++b) acc[a][b] = (floatx4){0.f, 0.f, 0.f, 0.f};

  auto stage_step = [&](int s, int b) {
    int k0 = s * 128;
    stage128<4>(&Aw[b][0], W1 + (size_t)m0 * 512 + k0, 512, tid);
    stage128<8>(&Xs[b][0], skipbf + (size_t)n0 * 512 + k0, 512, tid);
  };

  stage_step(0, 0);
  for (int s = 0; s < 4; ++s) {
    __syncthreads();
    if (s < 3) stage_step(s + 1, (s + 1) & 1);
    const unsigned short* aw = &Aw[s & 1][0];
    const unsigned short* xs = &Xs[s & 1][0];
    #pragma unroll
    for (int j = 0; j < 4; ++j) {
      int cj = j * 4 + qd;
      short8 a[2], xv[4];
      a[0] = frag128(aw, wm + lm, cj);
      a[1] = frag128(aw, wm + 16 + lm, cj);
      #pragma unroll
      for (int nt = 0; nt < 4; ++nt) xv[nt] = frag128(xs, wn + nt * 16 + lm, cj);
      #pragma unroll
      for (int mt = 0; mt < 2; ++mt)
        #pragma unroll
        for (int nt = 0; nt < 4; ++nt)
          acc[mt][nt] = MFMA_BF16(a[mt], xv[nt], acc[mt][nt]);
    }
  }

  #pragma unroll
  for (int mt = 0; mt < 2; ++mt) {
    int oc0 = m0 + wm + mt * 16 + qd * 4;
    floatx4 b4 = *(const floatx4*)&b1[oc0];
    #pragma unroll
    for (int nt = 0; nt < 4; ++nt) {
      int t = n0 + wn + nt * 16 + lm;
      ushort4v o4;
      #pragma unroll
      for (int r = 0; r < 4; ++r) {
        float v = acc[mt][nt][r] + b4[r];
        o4[r] = f2bf(v > 0.f ? v : 0.f);
      }
      *(ushort4v*)&t1[(size_t)t * 512 + oc0] = o4;
    }
  }
}

// ============ final2: one wave per t, coalesced + shuffle reduce ============
__global__ __launch_bounds__(256) void final2_kernel(
    const float* __restrict__ W2, const float* __restrict__ b2,
    const unsigned short* __restrict__ t1, float* __restrict__ out)
{
  int wave = threadIdx.x >> 6, lane = threadIdx.x & 63;
  int t = blockIdx.x * 4 + wave;
  short8 v = ld8(t1 + (size_t)t * 512 + lane * 8);
  float a0 = 0.f, a1 = 0.f;
  #pragma unroll
  for (int r = 0; r < 8; ++r) {
    float f = bf2f((unsigned short)v[r]);
    a0 += W2[lane * 8 + r] * f;
    a1 += W2[512 + lane * 8 + r] * f;
  }
  #pragma unroll
  for (int off = 32; off > 0; off >>= 1) {
    a0 += __shfl_xor(a0, off, 64);
    a1 += __shfl_xor(a1, off, 64);
  }
  if (lane == 0) {
    out[t] = a0 + b2[0];
    out[TLEN + t] = a1 + b2[1];
  }
}

extern "C" void kernel_launch(void* const* d_in, const int* in_sizes, int n_in,
                              void* d_out, int out_size, void* d_ws, size_t ws_size,
                              hipStream_t stream) {
  (void)in_sizes; (void)n_in; (void)out_size; (void)ws_size;
  const float* x       = (const float*)d_in[0];
  const float* c       = (const float*)d_in[1];
  const float* front_w = (const float*)d_in[2];
  const float* front_b = (const float*)d_in[3];
  const float* filt_w  = (const float*)d_in[4];
  const float* filt_b  = (const float*)d_in[5];
  const float* gate_w  = (const float*)d_in[6];
  const float* gate_b  = (const float*)d_in[7];
  const float* cf_w    = (const float*)d_in[8];
  const float* cf_b    = (const float*)d_in[9];
  const float* cg_w    = (const float*)d_in[10];
  const float* cg_b    = (const float*)d_in[11];
  const float* res_w   = (const float*)d_in[12];
  const float* res_b   = (const float*)d_in[13];
  const float* skip_w  = (const float*)d_in[14];
  const float* skip_b  = (const float*)d_in[15];
  const float* fin1_w  = (const float*)d_in[16];
  const float* fin1_b  = (const float*)d_in[17];
  const float* fin2_w  = (const float*)d_in[18];
  const float* fin2_b  = (const float*)d_in[19];
  const float* up_w    = (const float*)d_in[20];
  const float* up_b    = (const float*)d_in[21];

  char* ws = (char*)d_ws;
  auto alloc = [&](size_t bytes) {
    char* p = ws;
    ws += (bytes + 255) & ~(size_t)255;
    return p;
  };
  unsigned short* WA     = (unsigned short*)alloc((size_t)30 * 2 * 1024 * 512 * 2);
  unsigned short* RS     = (unsigned short*)alloc((size_t)30 * 1024 * 512 * 2);
  unsigned short* CA     = (unsigned short*)alloc((size_t)30 * 1024 * 128 * 2);
  unsigned short* F1c    = (unsigned short*)alloc((size_t)512 * 512 * 2);
  float* fgb             = (float*)alloc((size_t)30 * 1024 * 4);
  float* u1              = (float*)alloc((size_t)128 * 256 * 4);
  unsigned short* cu     = (unsigned short*)alloc((size_t)TLEN * 128 * 2);
  float* hf              = (float*)alloc((size_t)TLEN * 512 * 4);
  unsigned short* hbf    = (unsigned short*)alloc((size_t)(HPADT + TLEN) * 512 * 2);
  unsigned short* obf    = (unsigned short*)alloc((size_t)TLEN * 512 * 2);
  float* skip            = (float*)alloc((size_t)TLEN * 512 * 4);
  unsigned short* skipbf = (unsigned short*)alloc((size_t)TLEN * 512 * 2);
  unsigned short* t1     = (unsigned short*)alloc((size_t)TLEN * 512 * 2);
  float* out             = (float*)d_out;

  // zero the left pad of hbf (tap t-d reads 0 for t < d)
  hipMemsetAsync(hbf, 0, (size_t)HPADT * 512 * 2, stream);

  cast_all_kernel<<<17656, 256, 0, stream>>>(
      filt_w, gate_w, res_w, skip_w, cf_w, cg_w, fin1_w,
      filt_b, cf_b, gate_b, cg_b, WA, RS, CA, F1c, fgb);

  upsample1_kernel<<<dim3(128), 256, 0, stream>>>(c, up_w, up_b, u1);
  upsample2_kernel<<<dim3(16, 128), 256, 0, stream>>>(u1, up_w, up_b, cu);
  front_kernel<<<dim3(512, 2), 256, 0, stream>>>(x, front_w, front_b, hf, hbf);

  for (int l = 0; l < 30; ++l) {
    int d = 1 << (l % 10);
    gemm_a_kernel<<<dim3(32, 8), 256, 0, stream>>>(
        WA + (size_t)l * 2 * 524288, CA + (size_t)l * 131072,
        fgb + (size_t)l * 1024,
        hbf, cu, obf, d);
    gemm_b_kernel<<<dim3(32, 8), 256, 0, stream>>>(
        RS + (size_t)l * 524288,
        res_b + (size_t)l * 512, skip_b + (size_t)l * 512,
        obf, hf, hbf, skip, skipbf, (l == 0) ? 1 : 0, (l == 29) ? 1 : 0);
  }

  final1_kernel<<<dim3(32, 8), 256, 0, stream>>>(F1c, fin1_b, skipbf, t1);
  final2_kernel<<<1024, 256, 0, stream>>>(fin2_w, fin2_b, t1, out);
}